// Round 2
// baseline (1178.820 us; speedup 1.0000x reference)
//
#include <hip/hip_runtime.h>
#include <stdint.h>

typedef _Float16 f16x8 __attribute__((ext_vector_type(8)));
typedef _Float16 f16x4 __attribute__((ext_vector_type(4)));
typedef float    f32x4 __attribute__((ext_vector_type(4)));

__device__ __forceinline__ void load16_lds(const _Float16* g, _Float16* l) {
    __builtin_amdgcn_global_load_lds(
        (const __attribute__((address_space(1))) void*)g,
        (__attribute__((address_space(3))) void*)l, 16, 0, 0);
}

// ---------------------------------------------------------------- utilities

__global__ void k_cast(const float* __restrict__ in, _Float16* __restrict__ out, int n) {
    int i = (blockIdx.x * 256 + threadIdx.x) * 4;
    if (i < n) {
        float4 v = *reinterpret_cast<const float4*>(in + i);
        f16x4 o = { (_Float16)v.x, (_Float16)v.y, (_Float16)v.z, (_Float16)v.w };
        *reinterpret_cast<f16x4*>(out + i) = o;
    }
}

// rows of 2048, one block (256 thr) per row; writes f16 and optionally f32
__global__ __launch_bounds__(256) void k_rmsnorm(
    const float* __restrict__ x, const float* __restrict__ w,
    _Float16* __restrict__ oh, float* __restrict__ of)
{
    const int row = blockIdx.x, tid = threadIdx.x;
    const float* xr = x + (size_t)row * 2048;
    float4 a = *reinterpret_cast<const float4*>(xr + tid * 8);
    float4 b = *reinterpret_cast<const float4*>(xr + tid * 8 + 4);
    float ss = a.x*a.x + a.y*a.y + a.z*a.z + a.w*a.w
             + b.x*b.x + b.y*b.y + b.z*b.z + b.w*b.w;
    #pragma unroll
    for (int m = 1; m < 64; m <<= 1) ss += __shfl_xor(ss, m);
    __shared__ float red[4];
    if ((tid & 63) == 0) red[tid >> 6] = ss;
    __syncthreads();
    float tot = red[0] + red[1] + red[2] + red[3];
    float r = rsqrtf(tot * (1.f / 2048.f) + 1e-6f);
    float4 wa = *reinterpret_cast<const float4*>(w + tid * 8);
    float4 wb = *reinterpret_cast<const float4*>(w + tid * 8 + 4);
    float o0 = a.x*r*wa.x, o1 = a.y*r*wa.y, o2 = a.z*r*wa.z, o3 = a.w*r*wa.w;
    float o4 = b.x*r*wb.x, o5 = b.y*r*wb.y, o6 = b.z*r*wb.z, o7 = b.w*r*wb.w;
    f16x8 hv = { (_Float16)o0,(_Float16)o1,(_Float16)o2,(_Float16)o3,
                 (_Float16)o4,(_Float16)o5,(_Float16)o6,(_Float16)o7 };
    *reinterpret_cast<f16x8*>(oh + (size_t)row * 2048 + tid * 8) = hv;
    if (of) {
        float4 f0 = { o0, o1, o2, o3 }, f1 = { o4, o5, o6, o7 };
        *reinterpret_cast<float4*>(of + (size_t)row * 2048 + tid * 8) = f0;
        *reinterpret_cast<float4*>(of + (size_t)row * 2048 + tid * 8 + 4) = f1;
    }
}

// ---------------------------------------------------------------- generic GEMM
// C[r][c] = sum_k A[r][k] * W[c][k]  (+ resid). global_load_lds staging (m97).
__global__ __launch_bounds__(256) void k_gemm(
    const _Float16* __restrict__ A, int lda,
    const _Float16* __restrict__ W, int ldw,
    float* __restrict__ C, int ldc,
    const float* __restrict__ resid, int K)
{
    __shared__ __align__(16) _Float16 As[128][32];
    __shared__ __align__(16) _Float16 Ws[128][32];
    const int r0 = blockIdx.x * 128, c0 = blockIdx.y * 128;
    const int tid = threadIdx.x, lane = tid & 63, wid = tid >> 6;
    const int wr = wid >> 1, wc = wid & 1;
    const int sr = lane >> 2, scc = (lane & 3) * 8;
    const int fr = lane & 15, fk = (lane >> 4) * 8;
    const f32x4 z4 = { 0.f, 0.f, 0.f, 0.f };
    f32x4 acc[4][4];
    #pragma unroll
    for (int i = 0; i < 4; i++)
        #pragma unroll
        for (int j = 0; j < 4; j++) acc[i][j] = z4;

    for (int k0 = 0; k0 < K; k0 += 32) {
        #pragma unroll
        for (int i = 0; i < 2; i++) {
            int chunk = wid * 2 + i;
            load16_lds(A + (size_t)(r0 + chunk * 16 + sr) * lda + k0 + scc, &As[chunk * 16][0]);
            load16_lds(W + (size_t)(c0 + chunk * 16 + sr) * ldw + k0 + scc, &Ws[chunk * 16][0]);
        }
        __syncthreads();
        f16x8 af[4], bf[4];
        #pragma unroll
        for (int i = 0; i < 4; i++)
            af[i] = *reinterpret_cast<const f16x8*>(&As[wr * 64 + i * 16 + fr][fk]);
        #pragma unroll
        for (int j = 0; j < 4; j++)
            bf[j] = *reinterpret_cast<const f16x8*>(&Ws[wc * 64 + j * 16 + fr][fk]);
        #pragma unroll
        for (int i = 0; i < 4; i++)
            #pragma unroll
            for (int j = 0; j < 4; j++)
                acc[i][j] = __builtin_amdgcn_mfma_f32_16x16x32_f16(af[i], bf[j], acc[i][j], 0, 0, 0);
        __syncthreads();
    }
    #pragma unroll
    for (int i = 0; i < 4; i++) {
        const int rowb = r0 + wr * 64 + i * 16 + (lane >> 4) * 4;
        #pragma unroll
        for (int j = 0; j < 4; j++) {
            const int col = c0 + wc * 64 + j * 16 + fr;
            #pragma unroll
            for (int r = 0; r < 4; r++) {
                size_t idx = (size_t)(rowb + r) * ldc + col;
                float v = acc[i][j][r];
                if (resid) v += resid[idx];
                C[idx] = v;
            }
        }
    }
}

// ------------------------------------------- per-head RMSNorm + RoPE + V-transpose
__global__ __launch_bounds__(128) void k_qkv_post(
    const float* __restrict__ qf, const float* __restrict__ kf, const float* __restrict__ vf,
    const float* __restrict__ cosb, const float* __restrict__ sinb,
    const float* __restrict__ qn_w, const float* __restrict__ kn_w,
    _Float16* __restrict__ qh, _Float16* __restrict__ kh, _Float16* __restrict__ vth)
{
    const int tok = blockIdx.x, u = blockIdx.y, d = threadIdx.x;
    const int b = tok >> 10, l = tok & 1023;
    __shared__ float buf[128];
    __shared__ float r2[2];
    if (u < 32) {
        float val = qf[(size_t)tok * 4096 + u * 128 + d];
        float ss = val * val;
        #pragma unroll
        for (int m = 1; m < 64; m <<= 1) ss += __shfl_xor(ss, m);
        if ((d & 63) == 0) r2[d >> 6] = ss;
        __syncthreads();
        float rms = rsqrtf((r2[0] + r2[1]) * (1.f / 128.f) + 1e-6f);
        float nv = val * rms * qn_w[d];
        buf[d] = nv;
        __syncthreads();
        float rot = (d < 64) ? -buf[d + 64] : buf[d - 64];
        float o = cosb[(size_t)tok * 128 + d] * nv + sinb[(size_t)tok * 128 + d] * rot;
        qh[(size_t)tok * 4096 + u * 128 + d] = (_Float16)o;
    } else if (u < 36) {
        int kv = u - 32;
        float val = kf[(size_t)tok * 512 + kv * 128 + d];
        float ss = val * val;
        #pragma unroll
        for (int m = 1; m < 64; m <<= 1) ss += __shfl_xor(ss, m);
        if ((d & 63) == 0) r2[d >> 6] = ss;
        __syncthreads();
        float rms = rsqrtf((r2[0] + r2[1]) * (1.f / 128.f) + 1e-6f);
        float nv = val * rms * kn_w[d];
        buf[d] = nv;
        __syncthreads();
        float rot = (d < 64) ? -buf[d + 64] : buf[d - 64];
        float o = cosb[(size_t)tok * 128 + d] * nv + sinb[(size_t)tok * 128 + d] * rot;
        kh[(((size_t)b * 4 + kv) * 1024 + l) * 128 + d] = (_Float16)o;
    } else {
        int kv = u - 36;
        float val = vf[(size_t)tok * 512 + kv * 128 + d];
        vth[(((size_t)b * 4 + kv) * 128 + d) * 1024 + l] = (_Float16)val;
    }
}

// ---------------------------------------------------------------- attention
// Flash-style. grid (16 q-tiles of 64, B*H=128), block 256 = 4 independent
// waves; wave w owns q rows [qt*64+w*16, +16). Online softmax in registers,
// K/V^T read straight from global (L2-resident), P relayout via per-wave LDS.
__global__ __launch_bounds__(256) void k_attn(
    const _Float16* __restrict__ qh, const _Float16* __restrict__ kh,
    const _Float16* __restrict__ vth, _Float16* __restrict__ oh)
{
    const int qt = blockIdx.x, bh = blockIdx.y;
    const int b = bh >> 5, h = bh & 31, kv = h >> 3;
    const int tid = threadIdx.x, lane = tid & 63, wid = tid >> 6;
    const int q0 = qt * 64 + wid * 16;
    const int fr = lane & 15, fg = lane >> 4;
    __shared__ __align__(16) _Float16 Ps[4][16][72];

    const _Float16* qbase = qh + ((size_t)(b * 1024 + q0)) * 4096 + h * 128;
    f16x8 aq[4];
    #pragma unroll
    for (int kk = 0; kk < 4; kk++)
        aq[kk] = *reinterpret_cast<const f16x8*>(qbase + (size_t)fr * 4096 + kk * 32 + fg * 8);

    const _Float16* kb = kh + ((size_t)(b * 4 + kv)) * 1024 * 128;
    const _Float16* vb = vth + ((size_t)(b * 4 + kv)) * 128 * 1024;

    float m_r[4] = { -1e30f, -1e30f, -1e30f, -1e30f };
    float l_r[4] = { 0.f, 0.f, 0.f, 0.f };
    const f32x4 z4 = { 0.f, 0.f, 0.f, 0.f };
    f32x4 oacc[8];
    #pragma unroll
    for (int dj = 0; dj < 8; dj++) oacc[dj] = z4;

    const int nt = (q0 >> 6) + 1;
    for (int kt = 0; kt < nt; kt++) {
        const int key0 = kt * 64;
        f32x4 sc[4];
        #pragma unroll
        for (int j = 0; j < 4; j++) sc[j] = z4;
        #pragma unroll
        for (int j = 0; j < 4; j++) {
            const _Float16* krow = kb + (size_t)(key0 + j * 16 + fr) * 128;
            #pragma unroll
            for (int kk = 0; kk < 4; kk++) {
                f16x8 bk = *reinterpret_cast<const f16x8*>(krow + kk * 32 + fg * 8);
                sc[j] = __builtin_amdgcn_mfma_f32_16x16x32_f16(aq[kk], bk, sc[j], 0, 0, 0);
            }
        }
        const bool last = (kt == nt - 1);
        float pmax[4] = { -1e30f, -1e30f, -1e30f, -1e30f };
        #pragma unroll
        for (int j = 0; j < 4; j++) {
            const int key = key0 + j * 16 + fr;
            #pragma unroll
            for (int r = 0; r < 4; r++) {
                float v = sc[j][r] * 0.08838834764831845f;
                if (last && key > q0 + fg * 4 + r) v = -1e30f;
                sc[j][r] = v;
                pmax[r] = fmaxf(pmax[r], v);
            }
        }
        #pragma unroll
        for (int m = 1; m < 16; m <<= 1)
            #pragma unroll
            for (int r = 0; r < 4; r++) pmax[r] = fmaxf(pmax[r], __shfl_xor(pmax[r], m));
        float alpha[4];
        #pragma unroll
        for (int r = 0; r < 4; r++) {
            float mn = fmaxf(m_r[r], pmax[r]);
            alpha[r] = __expf(m_r[r] - mn);
            m_r[r] = mn;
        }
        float rs[4] = { 0.f, 0.f, 0.f, 0.f };
        #pragma unroll
        for (int j = 0; j < 4; j++)
            #pragma unroll
            for (int r = 0; r < 4; r++) {
                float p = __expf(sc[j][r] - m_r[r]);
                sc[j][r] = p;
                rs[r] += p;
            }
        #pragma unroll
        for (int m = 1; m < 16; m <<= 1)
            #pragma unroll
            for (int r = 0; r < 4; r++) rs[r] += __shfl_xor(rs[r], m);
        #pragma unroll
        for (int r = 0; r < 4; r++) l_r[r] = l_r[r] * alpha[r] + rs[r];
        #pragma unroll
        for (int dj = 0; dj < 8; dj++)
            #pragma unroll
            for (int r = 0; r < 4; r++) oacc[dj][r] *= alpha[r];
        #pragma unroll
        for (int j = 0; j < 4; j++)
            #pragma unroll
            for (int r = 0; r < 4; r++)
                Ps[wid][fg * 4 + r][j * 16 + fr] = (_Float16)sc[j][r];
        // same-wave LDS RAW: compiler inserts lgkmcnt wait, no barrier needed
        #pragma unroll
        for (int ks = 0; ks < 2; ks++) {
            f16x8 ap = *reinterpret_cast<const f16x8*>(&Ps[wid][fr][ks * 32 + fg * 8]);
            #pragma unroll
            for (int dj = 0; dj < 8; dj++) {
                f16x8 bv = *reinterpret_cast<const f16x8*>(
                    vb + (size_t)(dj * 16 + fr) * 1024 + key0 + ks * 32 + fg * 8);
                oacc[dj] = __builtin_amdgcn_mfma_f32_16x16x32_f16(ap, bv, oacc[dj], 0, 0, 0);
            }
        }
    }
    float inv[4];
    #pragma unroll
    for (int r = 0; r < 4; r++) inv[r] = 1.f / l_r[r];
    #pragma unroll
    for (int dj = 0; dj < 8; dj++)
        #pragma unroll
        for (int r = 0; r < 4; r++)
            oh[((size_t)(b * 1024 + q0 + fg * 4 + r)) * 4096 + h * 128 + dj * 16 + fr] =
                (_Float16)(oacc[dj][r] * inv[r]);
}

// ---------------------------------------------------------------- router
__global__ __launch_bounds__(256) void k_router(
    const float* __restrict__ hm, const float* __restrict__ rw,
    float* __restrict__ wdense)
{
    const int tok = blockIdx.x * 4 + (threadIdx.x >> 6);
    const int lane = threadIdx.x & 63;
    __shared__ float lg[4][16];
    const float* hr = hm + (size_t)tok * 2048;
    for (int e = 0; e < 16; e++) {
        float acc = 0.f;
        #pragma unroll
        for (int i = 0; i < 32; i++) acc += hr[i * 64 + lane] * rw[(size_t)e * 2048 + i * 64 + lane];
        #pragma unroll
        for (int m = 1; m < 64; m <<= 1) acc += __shfl_xor(acc, m);
        if (lane == 0) lg[threadIdx.x >> 6][e] = acc;
    }
    __syncthreads();
    if (lane == 0) {
        float* l = lg[threadIdx.x >> 6];
        float mx = l[0];
        for (int e = 1; e < 16; e++) mx = fmaxf(mx, l[e]);
        float p[16]; float sum = 0.f;
        for (int e = 0; e < 16; e++) { p[e] = expf(l[e] - mx); sum += p[e]; }
        for (int e = 0; e < 16; e++) p[e] /= sum;
        bool sel[16]; for (int e = 0; e < 16; e++) sel[e] = false;
        float ssum = 0.f;
        for (int t = 0; t < 8; t++) {
            int bi = -1; float bv = -1.f;
            for (int e = 0; e < 16; e++) if (!sel[e] && p[e] > bv) { bv = p[e]; bi = e; }
            sel[bi] = true; ssum += bv;
        }
        for (int e = 0; e < 16; e++)
            wdense[(size_t)e * 4096 + tok] = sel[e] ? p[e] / ssum : 0.f;
    }
}

// ---------------------------------------------------------------- MoE gate/up (fused SiLU)
__global__ __launch_bounds__(256) void k_moe_gu(
    const _Float16* __restrict__ hm, const _Float16* __restrict__ gw,
    const _Float16* __restrict__ uw, _Float16* __restrict__ ab)
{
    const int r0 = blockIdx.x * 128, e = blockIdx.y;
    const _Float16* G = gw + (size_t)e * 128 * 2048;
    const _Float16* U = uw + (size_t)e * 128 * 2048;
    __shared__ __align__(16) _Float16 As[128][32];
    __shared__ __align__(16) _Float16 Gs[128][32];
    __shared__ __align__(16) _Float16 Us[128][32];
    const int tid = threadIdx.x, lane = tid & 63, wid = tid >> 6;
    const int wr = wid >> 1, wc = wid & 1;
    const int sr = lane >> 2, scc = (lane & 3) * 8;
    const int fr = lane & 15, fk = (lane >> 4) * 8;
    const f32x4 z4 = { 0.f, 0.f, 0.f, 0.f };
    f32x4 ag[4][4], au[4][4];
    #pragma unroll
    for (int i = 0; i < 4; i++)
        #pragma unroll
        for (int j = 0; j < 4; j++) { ag[i][j] = z4; au[i][j] = z4; }

    for (int k0 = 0; k0 < 2048; k0 += 32) {
        #pragma unroll
        for (int i = 0; i < 2; i++) {
            int chunk = wid * 2 + i;
            load16_lds(hm + (size_t)(r0 + chunk * 16 + sr) * 2048 + k0 + scc, &As[chunk * 16][0]);
            load16_lds(G + (size_t)(chunk * 16 + sr) * 2048 + k0 + scc, &Gs[chunk * 16][0]);
            load16_lds(U + (size_t)(chunk * 16 + sr) * 2048 + k0 + scc, &Us[chunk * 16][0]);
        }
        __syncthreads();
        f16x8 af[4], bg[4], bu[4];
        #pragma unroll
        for (int i = 0; i < 4; i++)
            af[i] = *reinterpret_cast<const f16x8*>(&As[wr * 64 + i * 16 + fr][fk]);
        #pragma unroll
        for (int j = 0; j < 4; j++) {
            bg[j] = *reinterpret_cast<const f16x8*>(&Gs[wc * 64 + j * 16 + fr][fk]);
            bu[j] = *reinterpret_cast<const f16x8*>(&Us[wc * 64 + j * 16 + fr][fk]);
        }
        #pragma unroll
        for (int i = 0; i < 4; i++)
            #pragma unroll
            for (int j = 0; j < 4; j++) {
                ag[i][j] = __builtin_amdgcn_mfma_f32_16x16x32_f16(af[i], bg[j], ag[i][j], 0, 0, 0);
                au[i][j] = __builtin_amdgcn_mfma_f32_16x16x32_f16(af[i], bu[j], au[i][j], 0, 0, 0);
            }
        __syncthreads();
    }
    #pragma unroll
    for (int i = 0; i < 4; i++) {
        const int rowb = r0 + wr * 64 + i * 16 + (lane >> 4) * 4;
        #pragma unroll
        for (int j = 0; j < 4; j++) {
            const int col = wc * 64 + j * 16 + fr;
            #pragma unroll
            for (int r = 0; r < 4; r++) {
                float g = ag[i][j][r], uu = au[i][j][r];
                float sil = g / (1.f + __expf(-g));
                ab[((size_t)e * 4096 + rowb + r) * 128 + col] = (_Float16)(sil * uu);
            }
        }
    }
}

// ---------------------------------------------------------------- MoE down + both residuals
__global__ __launch_bounds__(256) void k_moe_down(
    const _Float16* __restrict__ ab, const _Float16* __restrict__ dw,
    const float* __restrict__ wdense, const float* __restrict__ x2,
    float* __restrict__ out)
{
    const int r0 = blockIdx.x * 128, c0 = blockIdx.y * 128;
    __shared__ __align__(16) _Float16 As[128][32];
    __shared__ __align__(16) _Float16 Ws[128][32];
    const int tid = threadIdx.x, lane = tid & 63, wid = tid >> 6;
    const int wr = wid >> 1, wc = wid & 1;
    const int sr = lane >> 2, scc = (lane & 3) * 8;
    const int fr = lane & 15, fk = (lane >> 4) * 8;
    const f32x4 z4 = { 0.f, 0.f, 0.f, 0.f };
    f32x4 acc[4][4];
    #pragma unroll
    for (int i = 0; i < 4; i++)
        #pragma unroll
        for (int j = 0; j < 4; j++) acc[i][j] = z4;

    for (int e = 0; e < 16; e++) {
        const _Float16* A = ab + (size_t)e * 4096 * 128;
        const _Float16* W = dw + (size_t)e * 2048 * 128;
        f32x4 pa[4][4];
        #pragma unroll
        for (int i = 0; i < 4; i++)
            #pragma unroll
            for (int j = 0; j < 4; j++) pa[i][j] = z4;
        for (int k0 = 0; k0 < 128; k0 += 32) {
            #pragma unroll
            for (int i = 0; i < 2; i++) {
                int chunk = wid * 2 + i;
                load16_lds(A + (size_t)(r0 + chunk * 16 + sr) * 128 + k0 + scc, &As[chunk * 16][0]);
                load16_lds(W + (size_t)(c0 + chunk * 16 + sr) * 128 + k0 + scc, &Ws[chunk * 16][0]);
            }
            __syncthreads();
            f16x8 af[4], bf[4];
            #pragma unroll
            for (int i = 0; i < 4; i++)
                af[i] = *reinterpret_cast<const f16x8*>(&As[wr * 64 + i * 16 + fr][fk]);
            #pragma unroll
            for (int j = 0; j < 4; j++)
                bf[j] = *reinterpret_cast<const f16x8*>(&Ws[wc * 64 + j * 16 + fr][fk]);
            #pragma unroll
            for (int i = 0; i < 4; i++)
                #pragma unroll
                for (int j = 0; j < 4; j++)
                    pa[i][j] = __builtin_amdgcn_mfma_f32_16x16x32_f16(af[i], bf[j], pa[i][j], 0, 0, 0);
            __syncthreads();
        }
        #pragma unroll
        for (int i = 0; i < 4; i++) {
            const int rowb = r0 + wr * 64 + i * 16 + (lane >> 4) * 4;
            float wv[4];
            #pragma unroll
            for (int r = 0; r < 4; r++) wv[r] = wdense[(size_t)e * 4096 + rowb + r];
            #pragma unroll
            for (int j = 0; j < 4; j++)
                #pragma unroll
                for (int r = 0; r < 4; r++) acc[i][j][r] += wv[r] * pa[i][j][r];
        }
    }
    #pragma unroll
    for (int i = 0; i < 4; i++) {
        const int rowb = r0 + wr * 64 + i * 16 + (lane >> 4) * 4;
        #pragma unroll
        for (int j = 0; j < 4; j++) {
            const int col = c0 + wc * 64 + j * 16 + fr;
            #pragma unroll
            for (int r = 0; r < 4; r++) {
                size_t idx = (size_t)(rowb + r) * 2048 + col;
                out[idx] = x2[idx] + acc[i][j][r];
            }
        }
    }
}

// ---------------------------------------------------------------- launch

extern "C" void kernel_launch(void* const* d_in, const int* in_sizes, int n_in,
                              void* d_out, int out_size, void* d_ws, size_t ws_size,
                              hipStream_t stream)
{
    const float* x        = (const float*)d_in[0];
    const float* cosb     = (const float*)d_in[1];
    const float* sinb     = (const float*)d_in[2];
    const float* nattn    = (const float*)d_in[3];
    const float* q_w      = (const float*)d_in[4];
    const float* k_w      = (const float*)d_in[5];
    const float* v_w      = (const float*)d_in[6];
    const float* qn_w     = (const float*)d_in[7];
    const float* kn_w     = (const float*)d_in[8];
    const float* o_w      = (const float*)d_in[9];
    const float* nmlp     = (const float*)d_in[10];
    const float* router_w = (const float*)d_in[11];
    const float* egw      = (const float*)d_in[12];
    const float* euw      = (const float*)d_in[13];
    const float* edw      = (const float*)d_in[14];

    char* w = (char*)d_ws;
    _Float16* qw_h = (_Float16*)(w + 0);           // 16.78 MB
    _Float16* kw_h = (_Float16*)(w + 16777216);    //  2.10 MB
    _Float16* vw_h = (_Float16*)(w + 18874368);    //  2.10 MB
    _Float16* ow_h = (_Float16*)(w + 20971520);    // 16.78 MB
    _Float16* gw_h = (_Float16*)(w + 37748736);    //  8.39 MB
    _Float16* uw_h = (_Float16*)(w + 46137344);    //  8.39 MB
    _Float16* dw_h = (_Float16*)(w + 54525952);    //  8.39 MB
    _Float16* h_h  = (_Float16*)(w + 62914560);    // 16.78 MB (reused as ab later)
    _Float16* ab_h = h_h;
    float*    q_f  = (float*)(w + 79691776);       // 67.11 MB
    float*    k_f  = (float*)(w + 146800640);      //  8.39 MB
    float*    v_f  = (float*)(w + 155189248);      //  8.39 MB
    _Float16* o_h  = (_Float16*)(w + 79691776);    // 33.55 MB (overlay q_f low)
    float*    x2   = (float*)(w + 113246208);      // 33.55 MB (overlay q_f high)
    _Float16* hm_h = (_Float16*)(w + 146800640);   // 16.78 MB (overlay k_f/v_f)
    _Float16* q_h  = (_Float16*)(w + 163577856);   // 33.55 MB
    float*    hm_f = (float*)(w + 163577856);      // overlay q_h after attention
    _Float16* k_h  = (_Float16*)(w + 197132288);   //  4.19 MB
    _Float16* vt_h = (_Float16*)(w + 201326592);   //  4.19 MB
    float*    wdense = (float*)(w + 205520896);    //  0.26 MB

    k_cast<<<8192, 256, 0, stream>>>(q_w, qw_h, 8388608);
    k_cast<<<1024, 256, 0, stream>>>(k_w, kw_h, 1048576);
    k_cast<<<1024, 256, 0, stream>>>(v_w, vw_h, 1048576);
    k_cast<<<8192, 256, 0, stream>>>(o_w, ow_h, 8388608);
    k_cast<<<4096, 256, 0, stream>>>(egw, gw_h, 4194304);
    k_cast<<<4096, 256, 0, stream>>>(euw, uw_h, 4194304);
    k_cast<<<4096, 256, 0, stream>>>(edw, dw_h, 4194304);
    k_rmsnorm<<<4096, 256, 0, stream>>>(x, nattn, h_h, nullptr);
    k_gemm<<<dim3(32, 32), 256, 0, stream>>>(h_h, 2048, qw_h, 2048, q_f, 4096, nullptr, 2048);
    k_gemm<<<dim3(32, 4),  256, 0, stream>>>(h_h, 2048, kw_h, 2048, k_f, 512,  nullptr, 2048);
    k_gemm<<<dim3(32, 4),  256, 0, stream>>>(h_h, 2048, vw_h, 2048, v_f, 512,  nullptr, 2048);
    k_qkv_post<<<dim3(4096, 40), 128, 0, stream>>>(q_f, k_f, v_f, cosb, sinb, qn_w, kn_w,
                                                   q_h, k_h, vt_h);
    k_attn<<<dim3(16, 128), 256, 0, stream>>>(q_h, k_h, vt_h, o_h);
    k_gemm<<<dim3(32, 16), 256, 0, stream>>>(o_h, 4096, ow_h, 4096, x2, 2048, x, 4096);
    k_rmsnorm<<<4096, 256, 0, stream>>>(x2, nmlp, hm_h, hm_f);
    k_router<<<1024, 256, 0, stream>>>(hm_f, router_w, wdense);
    k_moe_gu<<<dim3(32, 16), 256, 0, stream>>>(hm_h, gw_h, uw_h, ab_h);
    k_moe_down<<<dim3(32, 16), 256, 0, stream>>>(ab_h, dw_h, wdense, x2, (float*)d_out);

    (void)in_sizes; (void)n_in; (void)out_size; (void)ws_size;
}

// Round 3
// 799.690 us; speedup vs baseline: 1.4741x; 1.4741x over previous
//
#include <hip/hip_runtime.h>
#include <stdint.h>

typedef _Float16 f16x8 __attribute__((ext_vector_type(8)));
typedef _Float16 f16x4 __attribute__((ext_vector_type(4)));
typedef float    f32x4 __attribute__((ext_vector_type(4)));

__device__ __forceinline__ void load16_lds(const _Float16* g, _Float16* l) {
    __builtin_amdgcn_global_load_lds(
        (const __attribute__((address_space(1))) void*)g,
        (__attribute__((address_space(3))) void*)l, 16, 0, 0);
}

// ---------------------------------------------------------------- utilities

__global__ void k_cast(const float* __restrict__ in, _Float16* __restrict__ out, int n) {
    int i = (blockIdx.x * 256 + threadIdx.x) * 4;
    if (i < n) {
        float4 v = *reinterpret_cast<const float4*>(in + i);
        f16x4 o = { (_Float16)v.x, (_Float16)v.y, (_Float16)v.z, (_Float16)v.w };
        *reinterpret_cast<f16x4*>(out + i) = o;
    }
}

// rows of 2048, one block (256 thr) per row; writes f16 and optionally f32
__global__ __launch_bounds__(256) void k_rmsnorm(
    const float* __restrict__ x, const float* __restrict__ w,
    _Float16* __restrict__ oh, float* __restrict__ of)
{
    const int row = blockIdx.x, tid = threadIdx.x;
    const float* xr = x + (size_t)row * 2048;
    float4 a = *reinterpret_cast<const float4*>(xr + tid * 8);
    float4 b = *reinterpret_cast<const float4*>(xr + tid * 8 + 4);
    float ss = a.x*a.x + a.y*a.y + a.z*a.z + a.w*a.w
             + b.x*b.x + b.y*b.y + b.z*b.z + b.w*b.w;
    #pragma unroll
    for (int m = 1; m < 64; m <<= 1) ss += __shfl_xor(ss, m);
    __shared__ float red[4];
    if ((tid & 63) == 0) red[tid >> 6] = ss;
    __syncthreads();
    float tot = red[0] + red[1] + red[2] + red[3];
    float r = rsqrtf(tot * (1.f / 2048.f) + 1e-6f);
    float4 wa = *reinterpret_cast<const float4*>(w + tid * 8);
    float4 wb = *reinterpret_cast<const float4*>(w + tid * 8 + 4);
    float o0 = a.x*r*wa.x, o1 = a.y*r*wa.y, o2 = a.z*r*wa.z, o3 = a.w*r*wa.w;
    float o4 = b.x*r*wb.x, o5 = b.y*r*wb.y, o6 = b.z*r*wb.z, o7 = b.w*r*wb.w;
    f16x8 hv = { (_Float16)o0,(_Float16)o1,(_Float16)o2,(_Float16)o3,
                 (_Float16)o4,(_Float16)o5,(_Float16)o6,(_Float16)o7 };
    *reinterpret_cast<f16x8*>(oh + (size_t)row * 2048 + tid * 8) = hv;
    if (of) {
        float4 f0 = { o0, o1, o2, o3 }, f1 = { o4, o5, o6, o7 };
        *reinterpret_cast<float4*>(of + (size_t)row * 2048 + tid * 8) = f0;
        *reinterpret_cast<float4*>(of + (size_t)row * 2048 + tid * 8 + 4) = f1;
    }
}

// ---------------------------------------------------------------- generic GEMM
__global__ __launch_bounds__(256) void k_gemm(
    const _Float16* __restrict__ A, int lda,
    const _Float16* __restrict__ W, int ldw,
    float* __restrict__ C, int ldc,
    const float* __restrict__ resid, int K)
{
    __shared__ __align__(16) _Float16 As[128][32];
    __shared__ __align__(16) _Float16 Ws[128][32];
    const int r0 = blockIdx.x * 128, c0 = blockIdx.y * 128;
    const int tid = threadIdx.x, lane = tid & 63, wid = tid >> 6;
    const int wr = wid >> 1, wc = wid & 1;
    const int sr = lane >> 2, scc = (lane & 3) * 8;
    const int fr = lane & 15, fk = (lane >> 4) * 8;
    const f32x4 z4 = { 0.f, 0.f, 0.f, 0.f };
    f32x4 acc[4][4];
    #pragma unroll
    for (int i = 0; i < 4; i++)
        #pragma unroll
        for (int j = 0; j < 4; j++) acc[i][j] = z4;

    for (int k0 = 0; k0 < K; k0 += 32) {
        #pragma unroll
        for (int i = 0; i < 2; i++) {
            int chunk = wid * 2 + i;
            load16_lds(A + (size_t)(r0 + chunk * 16 + sr) * lda + k0 + scc, &As[chunk * 16][0]);
            load16_lds(W + (size_t)(c0 + chunk * 16 + sr) * ldw + k0 + scc, &Ws[chunk * 16][0]);
        }
        __syncthreads();
        f16x8 af[4], bf[4];
        #pragma unroll
        for (int i = 0; i < 4; i++)
            af[i] = *reinterpret_cast<const f16x8*>(&As[wr * 64 + i * 16 + fr][fk]);
        #pragma unroll
        for (int j = 0; j < 4; j++)
            bf[j] = *reinterpret_cast<const f16x8*>(&Ws[wc * 64 + j * 16 + fr][fk]);
        #pragma unroll
        for (int i = 0; i < 4; i++)
            #pragma unroll
            for (int j = 0; j < 4; j++)
                acc[i][j] = __builtin_amdgcn_mfma_f32_16x16x32_f16(af[i], bf[j], acc[i][j], 0, 0, 0);
        __syncthreads();
    }
    #pragma unroll
    for (int i = 0; i < 4; i++) {
        const int rowb = r0 + wr * 64 + i * 16 + (lane >> 4) * 4;
        #pragma unroll
        for (int j = 0; j < 4; j++) {
            const int col = c0 + wc * 64 + j * 16 + fr;
            #pragma unroll
            for (int r = 0; r < 4; r++) {
                size_t idx = (size_t)(rowb + r) * ldc + col;
                float v = acc[i][j][r];
                if (resid) v += resid[idx];
                C[idx] = v;
            }
        }
    }
}

// ------------------------------------------- per-head RMSNorm + RoPE + V-transpose
__global__ __launch_bounds__(128) void k_qkv_post(
    const float* __restrict__ qf, const float* __restrict__ kf, const float* __restrict__ vf,
    const float* __restrict__ cosb, const float* __restrict__ sinb,
    const float* __restrict__ qn_w, const float* __restrict__ kn_w,
    _Float16* __restrict__ qh, _Float16* __restrict__ kh, _Float16* __restrict__ vth)
{
    const int tok = blockIdx.x, u = blockIdx.y, d = threadIdx.x;
    const int b = tok >> 10, l = tok & 1023;
    __shared__ float buf[128];
    __shared__ float r2[2];
    if (u < 32) {
        float val = qf[(size_t)tok * 4096 + u * 128 + d];
        float ss = val * val;
        #pragma unroll
        for (int m = 1; m < 64; m <<= 1) ss += __shfl_xor(ss, m);
        if ((d & 63) == 0) r2[d >> 6] = ss;
        __syncthreads();
        float rms = rsqrtf((r2[0] + r2[1]) * (1.f / 128.f) + 1e-6f);
        float nv = val * rms * qn_w[d];
        buf[d] = nv;
        __syncthreads();
        float rot = (d < 64) ? -buf[d + 64] : buf[d - 64];
        float o = cosb[(size_t)tok * 128 + d] * nv + sinb[(size_t)tok * 128 + d] * rot;
        qh[(size_t)tok * 4096 + u * 128 + d] = (_Float16)o;
    } else if (u < 36) {
        int kv = u - 32;
        float val = kf[(size_t)tok * 512 + kv * 128 + d];
        float ss = val * val;
        #pragma unroll
        for (int m = 1; m < 64; m <<= 1) ss += __shfl_xor(ss, m);
        if ((d & 63) == 0) r2[d >> 6] = ss;
        __syncthreads();
        float rms = rsqrtf((r2[0] + r2[1]) * (1.f / 128.f) + 1e-6f);
        float nv = val * rms * kn_w[d];
        buf[d] = nv;
        __syncthreads();
        float rot = (d < 64) ? -buf[d + 64] : buf[d - 64];
        float o = cosb[(size_t)tok * 128 + d] * nv + sinb[(size_t)tok * 128 + d] * rot;
        kh[(((size_t)b * 4 + kv) * 1024 + l) * 128 + d] = (_Float16)o;
    } else {
        int kv = u - 36;
        float val = vf[(size_t)tok * 512 + kv * 128 + d];
        vth[(((size_t)b * 4 + kv) * 128 + d) * 1024 + l] = (_Float16)val;
    }
}

// ---------------------------------------------------------------- attention
// grid (bh=128, 16). g = 15 - blockIdx.y (longest blocks dispatched first).
// Block handles q rows [g*64, g*64+64): wave wid owns 16 rows. Per KV-tile of
// 64 keys: K[64][128] and V^T[128][64] staged cooperatively into LDS via
// global_load_lds with XOR-swizzled source (rule #21: swizzle both sides).
// Online softmax in registers; P relayout via per-wave padded LDS.
__global__ __launch_bounds__(256) void k_attn(
    const _Float16* __restrict__ qh, const _Float16* __restrict__ kh,
    const _Float16* __restrict__ vth, _Float16* __restrict__ oh)
{
    const int bh = blockIdx.x;
    const int g = 15 - blockIdx.y;
    const int b = bh >> 5, h = bh & 31, kv = h >> 3;
    const int tid = threadIdx.x, lane = tid & 63, wid = tid >> 6;
    const int fr = lane & 15, fg = lane >> 4;
    const int q0w = g * 64 + wid * 16;

    __shared__ __align__(16) _Float16 Ks[64][128];   // 16 KB, XOR-swizzled
    __shared__ __align__(16) _Float16 Vs[128][64];   // 16 KB, XOR-swizzled
    __shared__ __align__(16) _Float16 Ps[4][16][72]; //  9 KB, +8 pad

    const _Float16* kb = kh + ((size_t)(b * 4 + kv)) * 1024 * 128;
    const _Float16* vb = vth + ((size_t)(b * 4 + kv)) * 128 * 1024;

    // Q fragment, held in registers for the whole block
    f16x8 aq[4];
    {
        const _Float16* qbase = qh + ((size_t)(b * 1024 + q0w + fr)) * 4096 + h * 128;
        #pragma unroll
        for (int kk = 0; kk < 4; kk++)
            aq[kk] = *reinterpret_cast<const f16x8*>(qbase + kk * 32 + fg * 8);
    }

    float m_r[4] = { -1e30f, -1e30f, -1e30f, -1e30f };
    float l_r[4] = { 0.f, 0.f, 0.f, 0.f };
    const f32x4 z4 = { 0.f, 0.f, 0.f, 0.f };
    f32x4 oacc[8];
    #pragma unroll
    for (int dj = 0; dj < 8; dj++) oacc[dj] = z4;

    const int ntiles = g + 1;
    for (int kt = 0; kt < ntiles; kt++) {
        const int key0 = kt * 64;
        // ---- stage K tile: rows 16*wid..+15, 4 issues x 4 rows
        #pragma unroll
        for (int i = 0; i < 4; i++) {
            int rr = 16 * wid + 4 * i + (lane >> 4);
            int c16 = (lane & 15) ^ (rr & 7);
            load16_lds(kb + (size_t)(key0 + rr) * 128 + c16 * 8,
                       &Ks[0][0] + (16 * wid + 4 * i) * 128);
        }
        // ---- stage V^T tile: rows 32*wid..+31, 4 issues x 8 rows
        #pragma unroll
        for (int i = 0; i < 4; i++) {
            int rr = 32 * wid + 8 * i + (lane >> 3);
            int c16 = (lane & 7) ^ (rr & 7);
            load16_lds(vb + (size_t)rr * 1024 + key0 + c16 * 8,
                       &Vs[0][0] + (32 * wid + 8 * i) * 64);
        }
        __syncthreads();

        // ---- QK^T from LDS (swizzled read)
        f32x4 sc[4];
        #pragma unroll
        for (int j = 0; j < 4; j++) sc[j] = z4;
        #pragma unroll
        for (int j = 0; j < 4; j++) {
            #pragma unroll
            for (int kk = 0; kk < 4; kk++) {
                f16x8 bk = *reinterpret_cast<const f16x8*>(
                    &Ks[0][0] + (j * 16 + fr) * 128 + (((kk * 4 + fg) ^ (fr & 7)) * 8));
                sc[j] = __builtin_amdgcn_mfma_f32_16x16x32_f16(aq[kk], bk, sc[j], 0, 0, 0);
            }
        }

        // ---- online softmax (per 16-lane group; fr = key, fg*4+r = row)
        const bool lastt = (kt == ntiles - 1);
        float pmax[4] = { -1e30f, -1e30f, -1e30f, -1e30f };
        #pragma unroll
        for (int j = 0; j < 4; j++) {
            const int key = key0 + j * 16 + fr;
            #pragma unroll
            for (int r = 0; r < 4; r++) {
                float v = sc[j][r] * 0.08838834764831845f;
                if (lastt && key > q0w + fg * 4 + r) v = -1e30f;
                sc[j][r] = v;
                pmax[r] = fmaxf(pmax[r], v);
            }
        }
        #pragma unroll
        for (int m = 1; m < 16; m <<= 1)
            #pragma unroll
            for (int r = 0; r < 4; r++) pmax[r] = fmaxf(pmax[r], __shfl_xor(pmax[r], m));
        float alpha[4];
        #pragma unroll
        for (int r = 0; r < 4; r++) {
            float mn = fmaxf(m_r[r], pmax[r]);
            alpha[r] = __expf(m_r[r] - mn);
            m_r[r] = mn;
        }
        float rs[4] = { 0.f, 0.f, 0.f, 0.f };
        #pragma unroll
        for (int j = 0; j < 4; j++)
            #pragma unroll
            for (int r = 0; r < 4; r++) {
                float p = __expf(sc[j][r] - m_r[r]);
                sc[j][r] = p;
                rs[r] += p;
            }
        #pragma unroll
        for (int m = 1; m < 16; m <<= 1)
            #pragma unroll
            for (int r = 0; r < 4; r++) rs[r] += __shfl_xor(rs[r], m);
        #pragma unroll
        for (int r = 0; r < 4; r++) l_r[r] = l_r[r] * alpha[r] + rs[r];
        #pragma unroll
        for (int dj = 0; dj < 8; dj++)
            #pragma unroll
            for (int r = 0; r < 4; r++) oacc[dj][r] *= alpha[r];

        // ---- P relayout via per-wave LDS (same-wave RAW, no barrier)
        #pragma unroll
        for (int j = 0; j < 4; j++)
            #pragma unroll
            for (int r = 0; r < 4; r++)
                Ps[wid][fg * 4 + r][j * 16 + fr] = (_Float16)sc[j][r];

        // ---- PV from LDS (swizzled V read)
        #pragma unroll
        for (int ks = 0; ks < 2; ks++) {
            f16x8 ap = *reinterpret_cast<const f16x8*>(&Ps[wid][fr][ks * 32 + fg * 8]);
            #pragma unroll
            for (int dj = 0; dj < 8; dj++) {
                f16x8 bv = *reinterpret_cast<const f16x8*>(
                    &Vs[0][0] + (dj * 16 + fr) * 64 + (((ks * 4 + fg) ^ (fr & 7)) * 8));
                oacc[dj] = __builtin_amdgcn_mfma_f32_16x16x32_f16(ap, bv, oacc[dj], 0, 0, 0);
            }
        }
        __syncthreads();   // K/V LDS reads done before next stage overwrites
    }

    float inv[4];
    #pragma unroll
    for (int r = 0; r < 4; r++) inv[r] = 1.f / l_r[r];
    #pragma unroll
    for (int dj = 0; dj < 8; dj++)
        #pragma unroll
        for (int r = 0; r < 4; r++)
            oh[((size_t)(b * 1024 + q0w + fg * 4 + r)) * 4096 + h * 128 + dj * 16 + fr] =
                (_Float16)(oacc[dj][r] * inv[r]);
}

// ---------------------------------------------------------------- router
__global__ __launch_bounds__(256) void k_router(
    const float* __restrict__ hm, const float* __restrict__ rw,
    float* __restrict__ wdense)
{
    const int tok = blockIdx.x * 4 + (threadIdx.x >> 6);
    const int lane = threadIdx.x & 63;
    __shared__ float lg[4][16];
    const float* hr = hm + (size_t)tok * 2048;
    for (int e = 0; e < 16; e++) {
        float acc = 0.f;
        #pragma unroll
        for (int i = 0; i < 32; i++) acc += hr[i * 64 + lane] * rw[(size_t)e * 2048 + i * 64 + lane];
        #pragma unroll
        for (int m = 1; m < 64; m <<= 1) acc += __shfl_xor(acc, m);
        if (lane == 0) lg[threadIdx.x >> 6][e] = acc;
    }
    __syncthreads();
    if (lane == 0) {
        float* l = lg[threadIdx.x >> 6];
        float mx = l[0];
        for (int e = 1; e < 16; e++) mx = fmaxf(mx, l[e]);
        float p[16]; float sum = 0.f;
        for (int e = 0; e < 16; e++) { p[e] = expf(l[e] - mx); sum += p[e]; }
        for (int e = 0; e < 16; e++) p[e] /= sum;
        bool sel[16]; for (int e = 0; e < 16; e++) sel[e] = false;
        float ssum = 0.f;
        for (int t = 0; t < 8; t++) {
            int bi = -1; float bv = -1.f;
            for (int e = 0; e < 16; e++) if (!sel[e] && p[e] > bv) { bv = p[e]; bi = e; }
            sel[bi] = true; ssum += bv;
        }
        for (int e = 0; e < 16; e++)
            wdense[(size_t)e * 4096 + tok] = sel[e] ? p[e] / ssum : 0.f;
    }
}

// ---------------------------------------------------------------- MoE gate/up (fused SiLU)
__global__ __launch_bounds__(256) void k_moe_gu(
    const _Float16* __restrict__ hm, const _Float16* __restrict__ gw,
    const _Float16* __restrict__ uw, _Float16* __restrict__ ab)
{
    const int r0 = blockIdx.x * 128, e = blockIdx.y;
    const _Float16* G = gw + (size_t)e * 128 * 2048;
    const _Float16* U = uw + (size_t)e * 128 * 2048;
    __shared__ __align__(16) _Float16 As[128][32];
    __shared__ __align__(16) _Float16 Gs[128][32];
    __shared__ __align__(16) _Float16 Us[128][32];
    const int tid = threadIdx.x, lane = tid & 63, wid = tid >> 6;
    const int wr = wid >> 1, wc = wid & 1;
    const int sr = lane >> 2, scc = (lane & 3) * 8;
    const int fr = lane & 15, fk = (lane >> 4) * 8;
    const f32x4 z4 = { 0.f, 0.f, 0.f, 0.f };
    f32x4 ag[4][4], au[4][4];
    #pragma unroll
    for (int i = 0; i < 4; i++)
        #pragma unroll
        for (int j = 0; j < 4; j++) { ag[i][j] = z4; au[i][j] = z4; }

    for (int k0 = 0; k0 < 2048; k0 += 32) {
        #pragma unroll
        for (int i = 0; i < 2; i++) {
            int chunk = wid * 2 + i;
            load16_lds(hm + (size_t)(r0 + chunk * 16 + sr) * 2048 + k0 + scc, &As[chunk * 16][0]);
            load16_lds(G + (size_t)(chunk * 16 + sr) * 2048 + k0 + scc, &Gs[chunk * 16][0]);
            load16_lds(U + (size_t)(chunk * 16 + sr) * 2048 + k0 + scc, &Us[chunk * 16][0]);
        }
        __syncthreads();
        f16x8 af[4], bg[4], bu[4];
        #pragma unroll
        for (int i = 0; i < 4; i++)
            af[i] = *reinterpret_cast<const f16x8*>(&As[wr * 64 + i * 16 + fr][fk]);
        #pragma unroll
        for (int j = 0; j < 4; j++) {
            bg[j] = *reinterpret_cast<const f16x8*>(&Gs[wc * 64 + j * 16 + fr][fk]);
            bu[j] = *reinterpret_cast<const f16x8*>(&Us[wc * 64 + j * 16 + fr][fk]);
        }
        #pragma unroll
        for (int i = 0; i < 4; i++)
            #pragma unroll
            for (int j = 0; j < 4; j++) {
                ag[i][j] = __builtin_amdgcn_mfma_f32_16x16x32_f16(af[i], bg[j], ag[i][j], 0, 0, 0);
                au[i][j] = __builtin_amdgcn_mfma_f32_16x16x32_f16(af[i], bu[j], au[i][j], 0, 0, 0);
            }
        __syncthreads();
    }
    #pragma unroll
    for (int i = 0; i < 4; i++) {
        const int rowb = r0 + wr * 64 + i * 16 + (lane >> 4) * 4;
        #pragma unroll
        for (int j = 0; j < 4; j++) {
            const int col = wc * 64 + j * 16 + fr;
            #pragma unroll
            for (int r = 0; r < 4; r++) {
                float g = ag[i][j][r], uu = au[i][j][r];
                float sil = g / (1.f + __expf(-g));
                ab[((size_t)e * 4096 + rowb + r) * 128 + col] = (_Float16)(sil * uu);
            }
        }
    }
}

// ---------------------------------------------------------------- MoE down + both residuals
__global__ __launch_bounds__(256) void k_moe_down(
    const _Float16* __restrict__ ab, const _Float16* __restrict__ dw,
    const float* __restrict__ wdense, const float* __restrict__ x2,
    float* __restrict__ out)
{
    const int r0 = blockIdx.x * 128, c0 = blockIdx.y * 128;
    __shared__ __align__(16) _Float16 As[128][32];
    __shared__ __align__(16) _Float16 Ws[128][32];
    const int tid = threadIdx.x, lane = tid & 63, wid = tid >> 6;
    const int wr = wid >> 1, wc = wid & 1;
    const int sr = lane >> 2, scc = (lane & 3) * 8;
    const int fr = lane & 15, fk = (lane >> 4) * 8;
    const f32x4 z4 = { 0.f, 0.f, 0.f, 0.f };
    f32x4 acc[4][4];
    #pragma unroll
    for (int i = 0; i < 4; i++)
        #pragma unroll
        for (int j = 0; j < 4; j++) acc[i][j] = z4;

    for (int e = 0; e < 16; e++) {
        const _Float16* A = ab + (size_t)e * 4096 * 128;
        const _Float16* W = dw + (size_t)e * 2048 * 128;
        f32x4 pa[4][4];
        #pragma unroll
        for (int i = 0; i < 4; i++)
            #pragma unroll
            for (int j = 0; j < 4; j++) pa[i][j] = z4;
        for (int k0 = 0; k0 < 128; k0 += 32) {
            #pragma unroll
            for (int i = 0; i < 2; i++) {
                int chunk = wid * 2 + i;
                load16_lds(A + (size_t)(r0 + chunk * 16 + sr) * 128 + k0 + scc, &As[chunk * 16][0]);
                load16_lds(W + (size_t)(c0 + chunk * 16 + sr) * 128 + k0 + scc, &Ws[chunk * 16][0]);
            }
            __syncthreads();
            f16x8 af[4], bf[4];
            #pragma unroll
            for (int i = 0; i < 4; i++)
                af[i] = *reinterpret_cast<const f16x8*>(&As[wr * 64 + i * 16 + fr][fk]);
            #pragma unroll
            for (int j = 0; j < 4; j++)
                bf[j] = *reinterpret_cast<const f16x8*>(&Ws[wc * 64 + j * 16 + fr][fk]);
            #pragma unroll
            for (int i = 0; i < 4; i++)
                #pragma unroll
                for (int j = 0; j < 4; j++)
                    pa[i][j] = __builtin_amdgcn_mfma_f32_16x16x32_f16(af[i], bf[j], pa[i][j], 0, 0, 0);
            __syncthreads();
        }
        #pragma unroll
        for (int i = 0; i < 4; i++) {
            const int rowb = r0 + wr * 64 + i * 16 + (lane >> 4) * 4;
            float wv[4];
            #pragma unroll
            for (int r = 0; r < 4; r++) wv[r] = wdense[(size_t)e * 4096 + rowb + r];
            #pragma unroll
            for (int j = 0; j < 4; j++)
                #pragma unroll
                for (int r = 0; r < 4; r++) acc[i][j][r] += wv[r] * pa[i][j][r];
        }
    }
    #pragma unroll
    for (int i = 0; i < 4; i++) {
        const int rowb = r0 + wr * 64 + i * 16 + (lane >> 4) * 4;
        #pragma unroll
        for (int j = 0; j < 4; j++) {
            const int col = c0 + wc * 64 + j * 16 + fr;
            #pragma unroll
            for (int r = 0; r < 4; r++) {
                size_t idx = (size_t)(rowb + r) * 2048 + col;
                out[idx] = x2[idx] + acc[i][j][r];
            }
        }
    }
}

// ---------------------------------------------------------------- launch

extern "C" void kernel_launch(void* const* d_in, const int* in_sizes, int n_in,
                              void* d_out, int out_size, void* d_ws, size_t ws_size,
                              hipStream_t stream)
{
    const float* x        = (const float*)d_in[0];
    const float* cosb     = (const float*)d_in[1];
    const float* sinb     = (const float*)d_in[2];
    const float* nattn    = (const float*)d_in[3];
    const float* q_w      = (const float*)d_in[4];
    const float* k_w      = (const float*)d_in[5];
    const float* v_w      = (const float*)d_in[6];
    const float* qn_w     = (const float*)d_in[7];
    const float* kn_w     = (const float*)d_in[8];
    const float* o_w      = (const float*)d_in[9];
    const float* nmlp     = (const float*)d_in[10];
    const float* router_w = (const float*)d_in[11];
    const float* egw      = (const float*)d_in[12];
    const float* euw      = (const float*)d_in[13];
    const float* edw      = (const float*)d_in[14];

    char* w = (char*)d_ws;
    _Float16* qw_h = (_Float16*)(w + 0);           // 16.78 MB
    _Float16* kw_h = (_Float16*)(w + 16777216);    //  2.10 MB
    _Float16* vw_h = (_Float16*)(w + 18874368);    //  2.10 MB
    _Float16* ow_h = (_Float16*)(w + 20971520);    // 16.78 MB
    _Float16* gw_h = (_Float16*)(w + 37748736);    //  8.39 MB
    _Float16* uw_h = (_Float16*)(w + 46137344);    //  8.39 MB
    _Float16* dw_h = (_Float16*)(w + 54525952);    //  8.39 MB
    _Float16* h_h  = (_Float16*)(w + 62914560);    // 16.78 MB (reused as ab later)
    _Float16* ab_h = h_h;
    float*    q_f  = (float*)(w + 79691776);       // 67.11 MB
    float*    k_f  = (float*)(w + 146800640);      //  8.39 MB
    float*    v_f  = (float*)(w + 155189248);      //  8.39 MB
    _Float16* o_h  = (_Float16*)(w + 79691776);    // 33.55 MB (overlay q_f low)
    float*    x2   = (float*)(w + 113246208);      // 33.55 MB (overlay q_f high)
    _Float16* hm_h = (_Float16*)(w + 146800640);   // 16.78 MB (overlay k_f/v_f)
    _Float16* q_h  = (_Float16*)(w + 163577856);   // 33.55 MB
    float*    hm_f = (float*)(w + 163577856);      // overlay q_h after attention
    _Float16* k_h  = (_Float16*)(w + 197132288);   //  4.19 MB
    _Float16* vt_h = (_Float16*)(w + 201326592);   //  4.19 MB
    float*    wdense = (float*)(w + 205520896);    //  0.26 MB

    k_cast<<<8192, 256, 0, stream>>>(q_w, qw_h, 8388608);
    k_cast<<<1024, 256, 0, stream>>>(k_w, kw_h, 1048576);
    k_cast<<<1024, 256, 0, stream>>>(v_w, vw_h, 1048576);
    k_cast<<<8192, 256, 0, stream>>>(o_w, ow_h, 8388608);
    k_cast<<<4096, 256, 0, stream>>>(egw, gw_h, 4194304);
    k_cast<<<4096, 256, 0, stream>>>(euw, uw_h, 4194304);
    k_cast<<<4096, 256, 0, stream>>>(edw, dw_h, 4194304);
    k_rmsnorm<<<4096, 256, 0, stream>>>(x, nattn, h_h, nullptr);
    k_gemm<<<dim3(32, 32), 256, 0, stream>>>(h_h, 2048, qw_h, 2048, q_f, 4096, nullptr, 2048);
    k_gemm<<<dim3(32, 4),  256, 0, stream>>>(h_h, 2048, kw_h, 2048, k_f, 512,  nullptr, 2048);
    k_gemm<<<dim3(32, 4),  256, 0, stream>>>(h_h, 2048, vw_h, 2048, v_f, 512,  nullptr, 2048);
    k_qkv_post<<<dim3(4096, 40), 128, 0, stream>>>(q_f, k_f, v_f, cosb, sinb, qn_w, kn_w,
                                                   q_h, k_h, vt_h);
    k_attn<<<dim3(128, 16), 256, 0, stream>>>(q_h, k_h, vt_h, o_h);
    k_gemm<<<dim3(32, 16), 256, 0, stream>>>(o_h, 4096, ow_h, 4096, x2, 2048, x, 4096);
    k_rmsnorm<<<4096, 256, 0, stream>>>(x2, nmlp, hm_h, hm_f);
    k_router<<<1024, 256, 0, stream>>>(hm_f, router_w, wdense);
    k_moe_gu<<<dim3(32, 16), 256, 0, stream>>>(hm_h, gw_h, uw_h, ab_h);
    k_moe_down<<<dim3(32, 16), 256, 0, stream>>>(ab_h, dw_h, wdense, x2, (float*)d_out);

    (void)in_sizes; (void)n_in; (void)out_size; (void)ws_size;
}

// Round 4
// 623.697 us; speedup vs baseline: 1.8901x; 1.2822x over previous
//
#include <hip/hip_runtime.h>
#include <stdint.h>

typedef _Float16 f16x8 __attribute__((ext_vector_type(8)));
typedef _Float16 f16x4 __attribute__((ext_vector_type(4)));
typedef float    f32x4 __attribute__((ext_vector_type(4)));

__device__ __forceinline__ void load16_lds(const _Float16* g, _Float16* l) {
    __builtin_amdgcn_global_load_lds(
        (const __attribute__((address_space(1))) void*)g,
        (__attribute__((address_space(3))) void*)l, 16, 0, 0);
}

// ---------------------------------------------------------------- casts

__global__ void k_cast(const float* __restrict__ in, _Float16* __restrict__ out, int n) {
    int i = (blockIdx.x * 256 + threadIdx.x) * 4;
    if (i < n) {
        float4 v = *reinterpret_cast<const float4*>(in + i);
        f16x4 o = { (_Float16)v.x, (_Float16)v.y, (_Float16)v.z, (_Float16)v.w };
        *reinterpret_cast<f16x4*>(out + i) = o;
    }
}

// edw[e][dm][mi] (f32) -> dwc[dm][e*128+mi] (f16)
__global__ void k_cast_dw(const float* __restrict__ edw, _Float16* __restrict__ dwc) {
    int t = blockIdx.x * 256 + threadIdx.x;   // 16*2048*32 total
    int mi4 = (t & 31) * 4;
    int dm = (t >> 5) & 2047;
    int e = t >> 16;
    float4 v = *reinterpret_cast<const float4*>(edw + (((size_t)e * 2048 + dm) << 7) + mi4);
    f16x4 o = { (_Float16)v.x, (_Float16)v.y, (_Float16)v.z, (_Float16)v.w };
    *reinterpret_cast<f16x4*>(dwc + ((size_t)dm << 11) + e * 128 + mi4) = o;
}

// ---------------------------------------------------------------- rmsnorm
__global__ __launch_bounds__(256) void k_rmsnorm(
    const float* __restrict__ x, const float* __restrict__ w,
    _Float16* __restrict__ oh, float* __restrict__ of)
{
    const int row = blockIdx.x, tid = threadIdx.x;
    const float* xr = x + (size_t)row * 2048;
    float4 a = *reinterpret_cast<const float4*>(xr + tid * 8);
    float4 b = *reinterpret_cast<const float4*>(xr + tid * 8 + 4);
    float ss = a.x*a.x + a.y*a.y + a.z*a.z + a.w*a.w
             + b.x*b.x + b.y*b.y + b.z*b.z + b.w*b.w;
    #pragma unroll
    for (int m = 1; m < 64; m <<= 1) ss += __shfl_xor(ss, m);
    __shared__ float red[4];
    if ((tid & 63) == 0) red[tid >> 6] = ss;
    __syncthreads();
    float tot = red[0] + red[1] + red[2] + red[3];
    float r = rsqrtf(tot * (1.f / 2048.f) + 1e-6f);
    float4 wa = *reinterpret_cast<const float4*>(w + tid * 8);
    float4 wb = *reinterpret_cast<const float4*>(w + tid * 8 + 4);
    float o0 = a.x*r*wa.x, o1 = a.y*r*wa.y, o2 = a.z*r*wa.z, o3 = a.w*r*wa.w;
    float o4 = b.x*r*wb.x, o5 = b.y*r*wb.y, o6 = b.z*r*wb.z, o7 = b.w*r*wb.w;
    f16x8 hv = { (_Float16)o0,(_Float16)o1,(_Float16)o2,(_Float16)o3,
                 (_Float16)o4,(_Float16)o5,(_Float16)o6,(_Float16)o7 };
    *reinterpret_cast<f16x8*>(oh + (size_t)row * 2048 + tid * 8) = hv;
    if (of) {
        float4 f0 = { o0, o1, o2, o3 }, f1 = { o4, o5, o6, o7 };
        *reinterpret_cast<float4*>(of + (size_t)row * 2048 + tid * 8) = f0;
        *reinterpret_cast<float4*>(of + (size_t)row * 2048 + tid * 8 + 4) = f1;
    }
}

// ---------------------------------------------------------------- generic GEMM
// C = A @ W^T (+resid). 2-phase double-buffered global_load_lds staging.
// Output: f16 to Ch if Ch!=null else f32 to Cf.
__global__ __launch_bounds__(256) void k_gemm(
    const _Float16* __restrict__ A, int lda,
    const _Float16* __restrict__ W, int ldw,
    float* __restrict__ Cf, _Float16* __restrict__ Ch, int ldc,
    const float* __restrict__ resid, int K)
{
    __shared__ __align__(16) _Float16 As[2][128][32];
    __shared__ __align__(16) _Float16 Ws[2][128][32];
    const int r0 = blockIdx.x * 128, c0 = blockIdx.y * 128;
    const int tid = threadIdx.x, lane = tid & 63, wid = tid >> 6;
    const int wr = wid >> 1, wc = wid & 1;
    const int sr = lane >> 2, scc = (lane & 3) * 8;
    const int fr = lane & 15, fk = (lane >> 4) * 8;
    const f32x4 z4 = { 0.f, 0.f, 0.f, 0.f };
    f32x4 acc[4][4];
    #pragma unroll
    for (int i = 0; i < 4; i++)
        #pragma unroll
        for (int j = 0; j < 4; j++) acc[i][j] = z4;

    auto stage = [&](int bf, int k0) {
        #pragma unroll
        for (int i = 0; i < 2; i++) {
            int chunk = wid * 2 + i;
            load16_lds(A + (size_t)(r0 + chunk * 16 + sr) * lda + k0 + scc, &As[bf][chunk * 16][0]);
            load16_lds(W + (size_t)(c0 + chunk * 16 + sr) * ldw + k0 + scc, &Ws[bf][chunk * 16][0]);
        }
    };

    stage(0, 0);
    __syncthreads();
    const int nt = K >> 5;
    int cur = 0;
    for (int t = 0; t < nt; t++) {
        if (t + 1 < nt) stage(cur ^ 1, (t + 1) << 5);
        f16x8 af[4], bf4[4];
        #pragma unroll
        for (int i = 0; i < 4; i++)
            af[i] = *reinterpret_cast<const f16x8*>(&As[cur][wr * 64 + i * 16 + fr][fk]);
        #pragma unroll
        for (int j = 0; j < 4; j++)
            bf4[j] = *reinterpret_cast<const f16x8*>(&Ws[cur][wc * 64 + j * 16 + fr][fk]);
        #pragma unroll
        for (int i = 0; i < 4; i++)
            #pragma unroll
            for (int j = 0; j < 4; j++)
                acc[i][j] = __builtin_amdgcn_mfma_f32_16x16x32_f16(af[i], bf4[j], acc[i][j], 0, 0, 0);
        __syncthreads();
        cur ^= 1;
    }
    #pragma unroll
    for (int i = 0; i < 4; i++) {
        const int rowb = r0 + wr * 64 + i * 16 + (lane >> 4) * 4;
        #pragma unroll
        for (int j = 0; j < 4; j++) {
            const int col = c0 + wc * 64 + j * 16 + fr;
            #pragma unroll
            for (int r = 0; r < 4; r++) {
                size_t idx = (size_t)(rowb + r) * ldc + col;
                float v = acc[i][j][r];
                if (resid) v += resid[idx];
                if (Ch) Ch[idx] = (_Float16)v;
                else    Cf[idx] = v;
            }
        }
    }
}

// ------------------------------------------- per-head RMSNorm + RoPE + V-transpose
// reads merged qkv (f16, ld 5120). u<32: q head; u<36: k head; else v head.
__global__ __launch_bounds__(128) void k_qkv_post(
    const _Float16* __restrict__ qkv,
    const float* __restrict__ cosb, const float* __restrict__ sinb,
    const float* __restrict__ qn_w, const float* __restrict__ kn_w,
    _Float16* __restrict__ qh, _Float16* __restrict__ kh, _Float16* __restrict__ vth)
{
    const int tok = blockIdx.x, u = blockIdx.y, d = threadIdx.x;
    const int b = tok >> 10, l = tok & 1023;
    __shared__ float buf[128];
    __shared__ float r2[2];
    if (u < 32) {
        float val = (float)qkv[(size_t)tok * 5120 + u * 128 + d];
        float ss = val * val;
        #pragma unroll
        for (int m = 1; m < 64; m <<= 1) ss += __shfl_xor(ss, m);
        if ((d & 63) == 0) r2[d >> 6] = ss;
        __syncthreads();
        float rms = rsqrtf((r2[0] + r2[1]) * (1.f / 128.f) + 1e-6f);
        float nv = val * rms * qn_w[d];
        buf[d] = nv;
        __syncthreads();
        float rot = (d < 64) ? -buf[d + 64] : buf[d - 64];
        float o = cosb[(size_t)tok * 128 + d] * nv + sinb[(size_t)tok * 128 + d] * rot;
        qh[(size_t)tok * 4096 + u * 128 + d] = (_Float16)o;
    } else if (u < 36) {
        int kvh = u - 32;
        float val = (float)qkv[(size_t)tok * 5120 + 4096 + kvh * 128 + d];
        float ss = val * val;
        #pragma unroll
        for (int m = 1; m < 64; m <<= 1) ss += __shfl_xor(ss, m);
        if ((d & 63) == 0) r2[d >> 6] = ss;
        __syncthreads();
        float rms = rsqrtf((r2[0] + r2[1]) * (1.f / 128.f) + 1e-6f);
        float nv = val * rms * kn_w[d];
        buf[d] = nv;
        __syncthreads();
        float rot = (d < 64) ? -buf[d + 64] : buf[d - 64];
        float o = cosb[(size_t)tok * 128 + d] * nv + sinb[(size_t)tok * 128 + d] * rot;
        kh[(((size_t)b * 4 + kvh) * 1024 + l) * 128 + d] = (_Float16)o;
    } else {
        int kvh = u - 36;
        _Float16 val = qkv[(size_t)tok * 5120 + 4608 + kvh * 128 + d];
        vth[(((size_t)b * 4 + kvh) * 128 + d) * 1024 + l] = val;
    }
}

// ---------------------------------------------------------------- attention
__global__ __launch_bounds__(256) void k_attn(
    const _Float16* __restrict__ qh, const _Float16* __restrict__ kh,
    const _Float16* __restrict__ vth, _Float16* __restrict__ oh)
{
    const int bh = blockIdx.x;
    const int g = 15 - blockIdx.y;
    const int b = bh >> 5, h = bh & 31, kv = h >> 3;
    const int tid = threadIdx.x, lane = tid & 63, wid = tid >> 6;
    const int fr = lane & 15, fg = lane >> 4;
    const int q0w = g * 64 + wid * 16;

    __shared__ __align__(16) _Float16 Ks[64][128];
    __shared__ __align__(16) _Float16 Vs[128][64];
    __shared__ __align__(16) _Float16 Ps[4][16][72];

    const _Float16* kb = kh + ((size_t)(b * 4 + kv)) * 1024 * 128;
    const _Float16* vb = vth + ((size_t)(b * 4 + kv)) * 128 * 1024;

    f16x8 aq[4];
    {
        const _Float16* qbase = qh + ((size_t)(b * 1024 + q0w + fr)) * 4096 + h * 128;
        #pragma unroll
        for (int kk = 0; kk < 4; kk++)
            aq[kk] = *reinterpret_cast<const f16x8*>(qbase + kk * 32 + fg * 8);
    }

    float m_r[4] = { -1e30f, -1e30f, -1e30f, -1e30f };
    float l_r[4] = { 0.f, 0.f, 0.f, 0.f };
    const f32x4 z4 = { 0.f, 0.f, 0.f, 0.f };
    f32x4 oacc[8];
    #pragma unroll
    for (int dj = 0; dj < 8; dj++) oacc[dj] = z4;

    const int ntiles = g + 1;
    for (int kt = 0; kt < ntiles; kt++) {
        const int key0 = kt * 64;
        #pragma unroll
        for (int i = 0; i < 4; i++) {
            int rr = 16 * wid + 4 * i + (lane >> 4);
            int c16 = (lane & 15) ^ (rr & 7);
            load16_lds(kb + (size_t)(key0 + rr) * 128 + c16 * 8,
                       &Ks[0][0] + (16 * wid + 4 * i) * 128);
        }
        #pragma unroll
        for (int i = 0; i < 4; i++) {
            int rr = 32 * wid + 8 * i + (lane >> 3);
            int c16 = (lane & 7) ^ (rr & 7);
            load16_lds(vb + (size_t)rr * 1024 + key0 + c16 * 8,
                       &Vs[0][0] + (32 * wid + 8 * i) * 64);
        }
        __syncthreads();

        f32x4 sc[4];
        #pragma unroll
        for (int j = 0; j < 4; j++) sc[j] = z4;
        #pragma unroll
        for (int j = 0; j < 4; j++) {
            #pragma unroll
            for (int kk = 0; kk < 4; kk++) {
                f16x8 bk = *reinterpret_cast<const f16x8*>(
                    &Ks[0][0] + (j * 16 + fr) * 128 + (((kk * 4 + fg) ^ (fr & 7)) * 8));
                sc[j] = __builtin_amdgcn_mfma_f32_16x16x32_f16(aq[kk], bk, sc[j], 0, 0, 0);
            }
        }

        const bool lastt = (kt == ntiles - 1);
        float pmax[4] = { -1e30f, -1e30f, -1e30f, -1e30f };
        #pragma unroll
        for (int j = 0; j < 4; j++) {
            const int key = key0 + j * 16 + fr;
            #pragma unroll
            for (int r = 0; r < 4; r++) {
                float v = sc[j][r] * 0.08838834764831845f;
                if (lastt && key > q0w + fg * 4 + r) v = -1e30f;
                sc[j][r] = v;
                pmax[r] = fmaxf(pmax[r], v);
            }
        }
        #pragma unroll
        for (int m = 1; m < 16; m <<= 1)
            #pragma unroll
            for (int r = 0; r < 4; r++) pmax[r] = fmaxf(pmax[r], __shfl_xor(pmax[r], m));
        float alpha[4];
        #pragma unroll
        for (int r = 0; r < 4; r++) {
            float mn = fmaxf(m_r[r], pmax[r]);
            alpha[r] = __expf(m_r[r] - mn);
            m_r[r] = mn;
        }
        float rs[4] = { 0.f, 0.f, 0.f, 0.f };
        #pragma unroll
        for (int j = 0; j < 4; j++)
            #pragma unroll
            for (int r = 0; r < 4; r++) {
                float p = __expf(sc[j][r] - m_r[r]);
                sc[j][r] = p;
                rs[r] += p;
            }
        #pragma unroll
        for (int m = 1; m < 16; m <<= 1)
            #pragma unroll
            for (int r = 0; r < 4; r++) rs[r] += __shfl_xor(rs[r], m);
        #pragma unroll
        for (int r = 0; r < 4; r++) l_r[r] = l_r[r] * alpha[r] + rs[r];
        #pragma unroll
        for (int dj = 0; dj < 8; dj++)
            #pragma unroll
            for (int r = 0; r < 4; r++) oacc[dj][r] *= alpha[r];

        #pragma unroll
        for (int j = 0; j < 4; j++)
            #pragma unroll
            for (int r = 0; r < 4; r++)
                Ps[wid][fg * 4 + r][j * 16 + fr] = (_Float16)sc[j][r];

        #pragma unroll
        for (int ks = 0; ks < 2; ks++) {
            f16x8 ap = *reinterpret_cast<const f16x8*>(&Ps[wid][fr][ks * 32 + fg * 8]);
            #pragma unroll
            for (int dj = 0; dj < 8; dj++) {
                f16x8 bv = *reinterpret_cast<const f16x8*>(
                    &Vs[0][0] + (dj * 16 + fr) * 64 + (((ks * 4 + fg) ^ (fr & 7)) * 8));
                oacc[dj] = __builtin_amdgcn_mfma_f32_16x16x32_f16(ap, bv, oacc[dj], 0, 0, 0);
            }
        }
        __syncthreads();
    }

    float inv[4];
    #pragma unroll
    for (int r = 0; r < 4; r++) inv[r] = 1.f / l_r[r];
    #pragma unroll
    for (int dj = 0; dj < 8; dj++)
        #pragma unroll
        for (int r = 0; r < 4; r++)
            oh[((size_t)(b * 1024 + q0w + fg * 4 + r)) * 4096 + h * 128 + dj * 16 + fr] =
                (_Float16)(oacc[dj][r] * inv[r]);
}

// ---------------------------------------------------------------- router
__global__ __launch_bounds__(256) void k_router(
    const float* __restrict__ hm, const float* __restrict__ rw,
    float* __restrict__ wdense)
{
    const int tok = blockIdx.x * 4 + (threadIdx.x >> 6);
    const int lane = threadIdx.x & 63;
    __shared__ float lg[4][16];
    const float* hr = hm + (size_t)tok * 2048;
    for (int e = 0; e < 16; e++) {
        float acc = 0.f;
        #pragma unroll
        for (int i = 0; i < 32; i++) acc += hr[i * 64 + lane] * rw[(size_t)e * 2048 + i * 64 + lane];
        #pragma unroll
        for (int m = 1; m < 64; m <<= 1) acc += __shfl_xor(acc, m);
        if (lane == 0) lg[threadIdx.x >> 6][e] = acc;
    }
    __syncthreads();
    if (lane == 0) {
        float* l = lg[threadIdx.x >> 6];
        float mx = l[0];
        for (int e = 1; e < 16; e++) mx = fmaxf(mx, l[e]);
        float p[16]; float sum = 0.f;
        for (int e = 0; e < 16; e++) { p[e] = expf(l[e] - mx); sum += p[e]; }
        for (int e = 0; e < 16; e++) p[e] /= sum;
        bool sel[16]; for (int e = 0; e < 16; e++) sel[e] = false;
        float ssum = 0.f;
        for (int t = 0; t < 8; t++) {
            int bi = -1; float bv = -1.f;
            for (int e = 0; e < 16; e++) if (!sel[e] && p[e] > bv) { bv = p[e]; bi = e; }
            sel[bi] = true; ssum += bv;
        }
        for (int e = 0; e < 16; e++)
            wdense[(size_t)e * 4096 + tok] = sel[e] ? p[e] / ssum : 0.f;
    }
}

// ---------------------------------------------------------------- MoE gate/up
// writes ab[tok][e*128+mi] = wdense[e][tok] * silu(g) * u   (2-phase dbuf)
__global__ __launch_bounds__(256) void k_moe_gu(
    const _Float16* __restrict__ hm, const _Float16* __restrict__ gw,
    const _Float16* __restrict__ uw, const float* __restrict__ wdense,
    _Float16* __restrict__ ab)
{
    const int r0 = blockIdx.x * 128, e = blockIdx.y;
    const _Float16* G = gw + (size_t)e * 128 * 2048;
    const _Float16* U = uw + (size_t)e * 128 * 2048;
    __shared__ __align__(16) _Float16 As[2][128][32];
    __shared__ __align__(16) _Float16 Gs[2][128][32];
    __shared__ __align__(16) _Float16 Us[2][128][32];
    const int tid = threadIdx.x, lane = tid & 63, wid = tid >> 6;
    const int wr = wid >> 1, wc = wid & 1;
    const int sr = lane >> 2, scc = (lane & 3) * 8;
    const int fr = lane & 15, fk = (lane >> 4) * 8;
    const f32x4 z4 = { 0.f, 0.f, 0.f, 0.f };
    f32x4 ag[4][4], au[4][4];
    #pragma unroll
    for (int i = 0; i < 4; i++)
        #pragma unroll
        for (int j = 0; j < 4; j++) { ag[i][j] = z4; au[i][j] = z4; }

    auto stage = [&](int bf, int k0) {
        #pragma unroll
        for (int i = 0; i < 2; i++) {
            int chunk = wid * 2 + i;
            load16_lds(hm + (size_t)(r0 + chunk * 16 + sr) * 2048 + k0 + scc, &As[bf][chunk * 16][0]);
            load16_lds(G + (size_t)(chunk * 16 + sr) * 2048 + k0 + scc, &Gs[bf][chunk * 16][0]);
            load16_lds(U + (size_t)(chunk * 16 + sr) * 2048 + k0 + scc, &Us[bf][chunk * 16][0]);
        }
    };

    stage(0, 0);
    __syncthreads();
    int cur = 0;
    for (int t = 0; t < 64; t++) {
        if (t + 1 < 64) stage(cur ^ 1, (t + 1) << 5);
        f16x8 af[4], bg[4], bu[4];
        #pragma unroll
        for (int i = 0; i < 4; i++)
            af[i] = *reinterpret_cast<const f16x8*>(&As[cur][wr * 64 + i * 16 + fr][fk]);
        #pragma unroll
        for (int j = 0; j < 4; j++) {
            bg[j] = *reinterpret_cast<const f16x8*>(&Gs[cur][wc * 64 + j * 16 + fr][fk]);
            bu[j] = *reinterpret_cast<const f16x8*>(&Us[cur][wc * 64 + j * 16 + fr][fk]);
        }
        #pragma unroll
        for (int i = 0; i < 4; i++)
            #pragma unroll
            for (int j = 0; j < 4; j++) {
                ag[i][j] = __builtin_amdgcn_mfma_f32_16x16x32_f16(af[i], bg[j], ag[i][j], 0, 0, 0);
                au[i][j] = __builtin_amdgcn_mfma_f32_16x16x32_f16(af[i], bu[j], au[i][j], 0, 0, 0);
            }
        __syncthreads();
        cur ^= 1;
    }
    #pragma unroll
    for (int i = 0; i < 4; i++) {
        const int rowb = r0 + wr * 64 + i * 16 + (lane >> 4) * 4;
        float wv[4];
        #pragma unroll
        for (int r = 0; r < 4; r++) wv[r] = wdense[(size_t)e * 4096 + rowb + r];
        #pragma unroll
        for (int j = 0; j < 4; j++) {
            const int col = e * 128 + wc * 64 + j * 16 + fr;
            #pragma unroll
            for (int r = 0; r < 4; r++) {
                float g = ag[i][j][r], uu = au[i][j][r];
                float sil = g / (1.f + __expf(-g));
                ab[(size_t)(rowb + r) * 2048 + col] = (_Float16)(sil * uu * wv[r]);
            }
        }
    }
}

// ---------------------------------------------------------------- launch

extern "C" void kernel_launch(void* const* d_in, const int* in_sizes, int n_in,
                              void* d_out, int out_size, void* d_ws, size_t ws_size,
                              hipStream_t stream)
{
    const float* x        = (const float*)d_in[0];
    const float* cosb     = (const float*)d_in[1];
    const float* sinb     = (const float*)d_in[2];
    const float* nattn    = (const float*)d_in[3];
    const float* q_w      = (const float*)d_in[4];
    const float* k_w      = (const float*)d_in[5];
    const float* v_w      = (const float*)d_in[6];
    const float* qn_w     = (const float*)d_in[7];
    const float* kn_w     = (const float*)d_in[8];
    const float* o_w      = (const float*)d_in[9];
    const float* nmlp     = (const float*)d_in[10];
    const float* router_w = (const float*)d_in[11];
    const float* egw      = (const float*)d_in[12];
    const float* euw      = (const float*)d_in[13];
    const float* edw      = (const float*)d_in[14];

    char* w = (char*)d_ws;
    _Float16* qkvw_h = (_Float16*)(w + 0);          // 20.97 MB (q||k||v rows)
    _Float16* ow_h   = (_Float16*)(w + 20971520);   // 16.78 MB
    _Float16* gw_h   = (_Float16*)(w + 37748736);   //  8.39 MB
    _Float16* uw_h   = (_Float16*)(w + 46137344);   //  8.39 MB
    _Float16* dwc_h  = (_Float16*)(w + 54525952);   //  8.39 MB (permuted)
    _Float16* h_h    = (_Float16*)(w + 62914560);   // 16.78 MB (aliased hm_h)
    _Float16* hm_h   = h_h;
    float*    x2     = (float*)(w + 79691776);      // 33.55 MB
    _Float16* qkv_h  = (_Float16*)(w + 113246208);  // 41.94 MB (alias o_h, ab_h)
    _Float16* o_h    = qkv_h;
    _Float16* ab_h   = qkv_h;
    _Float16* q_h    = (_Float16*)(w + 155189248);  // 33.55 MB (alias hm_f)
    float*    hm_f   = (float*)(w + 155189248);
    _Float16* k_h    = (_Float16*)(w + 188743680);  //  4.19 MB
    _Float16* vt_h   = (_Float16*)(w + 192937984);  //  4.19 MB
    float*    wdense = (float*)(w + 197132288);     //  0.26 MB (total ~197.4 MB)

    // weights: fp16 casts (+ permuted down-proj)
    k_cast<<<8192, 256, 0, stream>>>(q_w, qkvw_h, 8388608);
    k_cast<<<1024, 256, 0, stream>>>(k_w, qkvw_h + (size_t)4096 * 2048, 1048576);
    k_cast<<<1024, 256, 0, stream>>>(v_w, qkvw_h + (size_t)4608 * 2048, 1048576);
    k_cast<<<8192, 256, 0, stream>>>(o_w, ow_h, 8388608);
    k_cast<<<4096, 256, 0, stream>>>(egw, gw_h, 4194304);
    k_cast<<<4096, 256, 0, stream>>>(euw, uw_h, 4194304);
    k_cast_dw<<<4096, 256, 0, stream>>>(edw, dwc_h);

    k_rmsnorm<<<4096, 256, 0, stream>>>(x, nattn, h_h, nullptr);
    // merged QKV projection -> f16
    k_gemm<<<dim3(32, 40), 256, 0, stream>>>(h_h, 2048, qkvw_h, 2048,
                                             nullptr, qkv_h, 5120, nullptr, 2048);
    k_qkv_post<<<dim3(4096, 40), 128, 0, stream>>>(qkv_h, cosb, sinb, qn_w, kn_w,
                                                   q_h, k_h, vt_h);
    k_attn<<<dim3(128, 16), 256, 0, stream>>>(q_h, k_h, vt_h, o_h);
    // O projection + residual -> x2 (f32)
    k_gemm<<<dim3(32, 16), 256, 0, stream>>>(o_h, 4096, ow_h, 4096,
                                             x2, nullptr, 2048, x, 4096);
    k_rmsnorm<<<4096, 256, 0, stream>>>(x2, nmlp, hm_h, hm_f);
    k_router<<<1024, 256, 0, stream>>>(hm_f, router_w, wdense);
    // gate/up + SiLU + router-weight scale -> ab [4096][2048]
    k_moe_gu<<<dim3(32, 16), 256, 0, stream>>>(hm_h, gw_h, uw_h, wdense, ab_h);
    // down projection as one GEMM + residual -> out
    k_gemm<<<dim3(32, 16), 256, 0, stream>>>(ab_h, 2048, dwc_h, 2048,
                                             (float*)d_out, nullptr, 2048, x2, 2048);

    (void)in_sizes; (void)n_in; (void)out_size; (void)ws_size;
}

// Round 5
// 616.858 us; speedup vs baseline: 1.9110x; 1.0111x over previous
//
#include <hip/hip_runtime.h>
#include <stdint.h>

typedef _Float16 f16x8 __attribute__((ext_vector_type(8)));
typedef _Float16 f16x4 __attribute__((ext_vector_type(4)));
typedef float    f32x4 __attribute__((ext_vector_type(4)));

__device__ __forceinline__ void load16_lds(const _Float16* g, _Float16* l) {
    __builtin_amdgcn_global_load_lds(
        (const __attribute__((address_space(1))) void*)g,
        (__attribute__((address_space(3))) void*)l, 16, 0, 0);
}

// ---------------------------------------------------------------- casts

__global__ void k_cast(const float* __restrict__ in, _Float16* __restrict__ out, int n) {
    int i = (blockIdx.x * 256 + threadIdx.x) * 4;
    if (i < n) {
        float4 v = *reinterpret_cast<const float4*>(in + i);
        f16x4 o = { (_Float16)v.x, (_Float16)v.y, (_Float16)v.z, (_Float16)v.w };
        *reinterpret_cast<f16x4*>(out + i) = o;
    }
}

// edw[e][dm][mi] (f32) -> dwc[dm][e*128+mi] (f16)
__global__ void k_cast_dw(const float* __restrict__ edw, _Float16* __restrict__ dwc) {
    int t = blockIdx.x * 256 + threadIdx.x;
    int mi4 = (t & 31) * 4;
    int dm = (t >> 5) & 2047;
    int e = t >> 16;
    float4 v = *reinterpret_cast<const float4*>(edw + (((size_t)e * 2048 + dm) << 7) + mi4);
    f16x4 o = { (_Float16)v.x, (_Float16)v.y, (_Float16)v.z, (_Float16)v.w };
    *reinterpret_cast<f16x4*>(dwc + ((size_t)dm << 11) + e * 128 + mi4) = o;
}

// ---------------------------------------------------------------- rmsnorm
__global__ __launch_bounds__(256) void k_rmsnorm(
    const float* __restrict__ x, const float* __restrict__ w,
    _Float16* __restrict__ oh, float* __restrict__ of)
{
    const int row = blockIdx.x, tid = threadIdx.x;
    const float* xr = x + (size_t)row * 2048;
    float4 a = *reinterpret_cast<const float4*>(xr + tid * 8);
    float4 b = *reinterpret_cast<const float4*>(xr + tid * 8 + 4);
    float ss = a.x*a.x + a.y*a.y + a.z*a.z + a.w*a.w
             + b.x*b.x + b.y*b.y + b.z*b.z + b.w*b.w;
    #pragma unroll
    for (int m = 1; m < 64; m <<= 1) ss += __shfl_xor(ss, m);
    __shared__ float red[4];
    if ((tid & 63) == 0) red[tid >> 6] = ss;
    __syncthreads();
    float tot = red[0] + red[1] + red[2] + red[3];
    float r = rsqrtf(tot * (1.f / 2048.f) + 1e-6f);
    float4 wa = *reinterpret_cast<const float4*>(w + tid * 8);
    float4 wb = *reinterpret_cast<const float4*>(w + tid * 8 + 4);
    float o0 = a.x*r*wa.x, o1 = a.y*r*wa.y, o2 = a.z*r*wa.z, o3 = a.w*r*wa.w;
    float o4 = b.x*r*wb.x, o5 = b.y*r*wb.y, o6 = b.z*r*wb.z, o7 = b.w*r*wb.w;
    f16x8 hv = { (_Float16)o0,(_Float16)o1,(_Float16)o2,(_Float16)o3,
                 (_Float16)o4,(_Float16)o5,(_Float16)o6,(_Float16)o7 };
    *reinterpret_cast<f16x8*>(oh + (size_t)row * 2048 + tid * 8) = hv;
    if (of) {
        float4 f0 = { o0, o1, o2, o3 }, f1 = { o4, o5, o6, o7 };
        *reinterpret_cast<float4*>(of + (size_t)row * 2048 + tid * 8) = f0;
        *reinterpret_cast<float4*>(of + (size_t)row * 2048 + tid * 8 + 4) = f1;
    }
}

// ---------------------------------------------------------------- generic GEMM
// C = A @ W^T (+resid). 3-buffer counted-vmcnt pipeline, XOR-swizzled LDS
// (swizzle on global source + on ds_read; LDS dest stays linear — rule #21).
__global__ __launch_bounds__(256) void k_gemm(
    const _Float16* __restrict__ A, int lda,
    const _Float16* __restrict__ W, int ldw,
    float* __restrict__ Cf, _Float16* __restrict__ Ch, int ldc,
    const float* __restrict__ resid, int K)
{
    __shared__ __align__(16) _Float16 As[3][128][32];
    __shared__ __align__(16) _Float16 Ws[3][128][32];
    const int r0 = blockIdx.x * 128, c0 = blockIdx.y * 128;
    const int tid = threadIdx.x, lane = tid & 63, wid = tid >> 6;
    const int wr = wid >> 1, wc = wid & 1;
    const int sr = lane >> 2;
    const int scs = ((lane & 3) ^ ((lane >> 3) & 3)) * 8;        // swizzled src chunk
    const int fr = lane & 15;
    const int rks = (((lane >> 4) ^ ((fr >> 1) & 3))) * 8;       // swizzled read chunk
    const f32x4 z4 = { 0.f, 0.f, 0.f, 0.f };
    f32x4 acc[4][4];
    #pragma unroll
    for (int i = 0; i < 4; i++)
        #pragma unroll
        for (int j = 0; j < 4; j++) acc[i][j] = z4;

    auto stage = [&](int bf, int k0) {
        #pragma unroll
        for (int i = 0; i < 2; i++) {
            int chunk = wid * 2 + i;
            load16_lds(A + (size_t)(r0 + chunk * 16 + sr) * lda + k0 + scs, &As[bf][chunk * 16][0]);
            load16_lds(W + (size_t)(c0 + chunk * 16 + sr) * ldw + k0 + scs, &Ws[bf][chunk * 16][0]);
        }
    };

    const int nt = K >> 5;
    stage(0, 0);
    if (nt > 1) stage(1, 32);
    int cur = 0;
    for (int t = 0; t < nt; t++) {
        if (t < nt - 1) asm volatile("s_waitcnt vmcnt(4)" ::: "memory");
        else            asm volatile("s_waitcnt vmcnt(0)" ::: "memory");
        __builtin_amdgcn_s_barrier();
        f16x8 af[4], bf4[4];
        #pragma unroll
        for (int i = 0; i < 4; i++)
            af[i] = *reinterpret_cast<const f16x8*>(&As[cur][wr * 64 + i * 16 + fr][rks]);
        #pragma unroll
        for (int j = 0; j < 4; j++)
            bf4[j] = *reinterpret_cast<const f16x8*>(&Ws[cur][wc * 64 + j * 16 + fr][rks]);
        if (t + 2 < nt) stage((t + 2) % 3, (t + 2) << 5);
        #pragma unroll
        for (int i = 0; i < 4; i++)
            #pragma unroll
            for (int j = 0; j < 4; j++)
                acc[i][j] = __builtin_amdgcn_mfma_f32_16x16x32_f16(af[i], bf4[j], acc[i][j], 0, 0, 0);
        cur = (cur + 1) % 3;
    }
    #pragma unroll
    for (int i = 0; i < 4; i++) {
        const int rowb = r0 + wr * 64 + i * 16 + (lane >> 4) * 4;
        #pragma unroll
        for (int j = 0; j < 4; j++) {
            const int col = c0 + wc * 64 + j * 16 + fr;
            #pragma unroll
            for (int r = 0; r < 4; r++) {
                size_t idx = (size_t)(rowb + r) * ldc + col;
                float v = acc[i][j][r];
                if (resid) v += resid[idx];
                if (Ch) Ch[idx] = (_Float16)v;
                else    Cf[idx] = v;
            }
        }
    }
}

// ------------------------------------------- per-head RMSNorm + RoPE + V-transpose
__global__ __launch_bounds__(128) void k_qkv_post(
    const _Float16* __restrict__ qkv,
    const float* __restrict__ cosb, const float* __restrict__ sinb,
    const float* __restrict__ qn_w, const float* __restrict__ kn_w,
    _Float16* __restrict__ qh, _Float16* __restrict__ kh, _Float16* __restrict__ vth)
{
    const int tok = blockIdx.x, u = blockIdx.y, d = threadIdx.x;
    const int b = tok >> 10, l = tok & 1023;
    __shared__ float buf[128];
    __shared__ float r2[2];
    if (u < 32) {
        float val = (float)qkv[(size_t)tok * 5120 + u * 128 + d];
        float ss = val * val;
        #pragma unroll
        for (int m = 1; m < 64; m <<= 1) ss += __shfl_xor(ss, m);
        if ((d & 63) == 0) r2[d >> 6] = ss;
        __syncthreads();
        float rms = rsqrtf((r2[0] + r2[1]) * (1.f / 128.f) + 1e-6f);
        float nv = val * rms * qn_w[d];
        buf[d] = nv;
        __syncthreads();
        float rot = (d < 64) ? -buf[d + 64] : buf[d - 64];
        float o = cosb[(size_t)tok * 128 + d] * nv + sinb[(size_t)tok * 128 + d] * rot;
        qh[(size_t)tok * 4096 + u * 128 + d] = (_Float16)o;
    } else if (u < 36) {
        int kvh = u - 32;
        float val = (float)qkv[(size_t)tok * 5120 + 4096 + kvh * 128 + d];
        float ss = val * val;
        #pragma unroll
        for (int m = 1; m < 64; m <<= 1) ss += __shfl_xor(ss, m);
        if ((d & 63) == 0) r2[d >> 6] = ss;
        __syncthreads();
        float rms = rsqrtf((r2[0] + r2[1]) * (1.f / 128.f) + 1e-6f);
        float nv = val * rms * kn_w[d];
        buf[d] = nv;
        __syncthreads();
        float rot = (d < 64) ? -buf[d + 64] : buf[d - 64];
        float o = cosb[(size_t)tok * 128 + d] * nv + sinb[(size_t)tok * 128 + d] * rot;
        kh[(((size_t)b * 4 + kvh) * 1024 + l) * 128 + d] = (_Float16)o;
    } else {
        int kvh = u - 36;
        _Float16 val = qkv[(size_t)tok * 5120 + 4608 + kvh * 128 + d];
        vth[(((size_t)b * 4 + kvh) * 128 + d) * 1024 + l] = val;
    }
}

// ---------------------------------------------------------------- attention
__global__ __launch_bounds__(256) void k_attn(
    const _Float16* __restrict__ qh, const _Float16* __restrict__ kh,
    const _Float16* __restrict__ vth, _Float16* __restrict__ oh)
{
    const int bh = blockIdx.x;
    const int g = 15 - blockIdx.y;
    const int b = bh >> 5, h = bh & 31, kv = h >> 3;
    const int tid = threadIdx.x, lane = tid & 63, wid = tid >> 6;
    const int fr = lane & 15, fg = lane >> 4;
    const int q0w = g * 64 + wid * 16;

    __shared__ __align__(16) _Float16 Ks[64][128];
    __shared__ __align__(16) _Float16 Vs[128][64];
    __shared__ __align__(16) _Float16 Ps[4][16][72];

    const _Float16* kb = kh + ((size_t)(b * 4 + kv)) * 1024 * 128;
    const _Float16* vb = vth + ((size_t)(b * 4 + kv)) * 128 * 1024;

    f16x8 aq[4];
    {
        const _Float16* qbase = qh + ((size_t)(b * 1024 + q0w + fr)) * 4096 + h * 128;
        #pragma unroll
        for (int kk = 0; kk < 4; kk++)
            aq[kk] = *reinterpret_cast<const f16x8*>(qbase + kk * 32 + fg * 8);
    }

    float m_r[4] = { -1e30f, -1e30f, -1e30f, -1e30f };
    float l_r[4] = { 0.f, 0.f, 0.f, 0.f };
    const f32x4 z4 = { 0.f, 0.f, 0.f, 0.f };
    f32x4 oacc[8];
    #pragma unroll
    for (int dj = 0; dj < 8; dj++) oacc[dj] = z4;

    const int ntiles = g + 1;
    for (int kt = 0; kt < ntiles; kt++) {
        const int key0 = kt * 64;
        #pragma unroll
        for (int i = 0; i < 4; i++) {
            int rr = 16 * wid + 4 * i + (lane >> 4);
            int c16 = (lane & 15) ^ (rr & 7);
            load16_lds(kb + (size_t)(key0 + rr) * 128 + c16 * 8,
                       &Ks[0][0] + (16 * wid + 4 * i) * 128);
        }
        #pragma unroll
        for (int i = 0; i < 4; i++) {
            int rr = 32 * wid + 8 * i + (lane >> 3);
            int c16 = (lane & 7) ^ (rr & 7);
            load16_lds(vb + (size_t)rr * 1024 + key0 + c16 * 8,
                       &Vs[0][0] + (32 * wid + 8 * i) * 64);
        }
        __syncthreads();

        f32x4 sc[4];
        #pragma unroll
        for (int j = 0; j < 4; j++) sc[j] = z4;
        #pragma unroll
        for (int j = 0; j < 4; j++) {
            #pragma unroll
            for (int kk = 0; kk < 4; kk++) {
                f16x8 bk = *reinterpret_cast<const f16x8*>(
                    &Ks[0][0] + (j * 16 + fr) * 128 + (((kk * 4 + fg) ^ (fr & 7)) * 8));
                sc[j] = __builtin_amdgcn_mfma_f32_16x16x32_f16(aq[kk], bk, sc[j], 0, 0, 0);
            }
        }

        const bool lastt = (kt == ntiles - 1);
        float pmax[4] = { -1e30f, -1e30f, -1e30f, -1e30f };
        #pragma unroll
        for (int j = 0; j < 4; j++) {
            const int key = key0 + j * 16 + fr;
            #pragma unroll
            for (int r = 0; r < 4; r++) {
                float v = sc[j][r] * 0.08838834764831845f;
                if (lastt && key > q0w + fg * 4 + r) v = -1e30f;
                sc[j][r] = v;
                pmax[r] = fmaxf(pmax[r], v);
            }
        }
        #pragma unroll
        for (int m = 1; m < 16; m <<= 1)
            #pragma unroll
            for (int r = 0; r < 4; r++) pmax[r] = fmaxf(pmax[r], __shfl_xor(pmax[r], m));
        float alpha[4];
        #pragma unroll
        for (int r = 0; r < 4; r++) {
            float mn = fmaxf(m_r[r], pmax[r]);
            alpha[r] = __expf(m_r[r] - mn);
            m_r[r] = mn;
        }
        float rs[4] = { 0.f, 0.f, 0.f, 0.f };
        #pragma unroll
        for (int j = 0; j < 4; j++)
            #pragma unroll
            for (int r = 0; r < 4; r++) {
                float p = __expf(sc[j][r] - m_r[r]);
                sc[j][r] = p;
                rs[r] += p;
            }
        #pragma unroll
        for (int m = 1; m < 16; m <<= 1)
            #pragma unroll
            for (int r = 0; r < 4; r++) rs[r] += __shfl_xor(rs[r], m);
        #pragma unroll
        for (int r = 0; r < 4; r++) l_r[r] = l_r[r] * alpha[r] + rs[r];
        #pragma unroll
        for (int dj = 0; dj < 8; dj++)
            #pragma unroll
            for (int r = 0; r < 4; r++) oacc[dj][r] *= alpha[r];

        #pragma unroll
        for (int j = 0; j < 4; j++)
            #pragma unroll
            for (int r = 0; r < 4; r++)
                Ps[wid][fg * 4 + r][j * 16 + fr] = (_Float16)sc[j][r];

        #pragma unroll
        for (int ks = 0; ks < 2; ks++) {
            f16x8 ap = *reinterpret_cast<const f16x8*>(&Ps[wid][fr][ks * 32 + fg * 8]);
            #pragma unroll
            for (int dj = 0; dj < 8; dj++) {
                f16x8 bv = *reinterpret_cast<const f16x8*>(
                    &Vs[0][0] + (dj * 16 + fr) * 64 + (((ks * 4 + fg) ^ (fr & 7)) * 8));
                oacc[dj] = __builtin_amdgcn_mfma_f32_16x16x32_f16(ap, bv, oacc[dj], 0, 0, 0);
            }
        }
        __syncthreads();
    }

    float inv[4];
    #pragma unroll
    for (int r = 0; r < 4; r++) inv[r] = 1.f / l_r[r];
    #pragma unroll
    for (int dj = 0; dj < 8; dj++)
        #pragma unroll
        for (int r = 0; r < 4; r++)
            oh[((size_t)(b * 1024 + q0w + fg * 4 + r)) * 4096 + h * 128 + dj * 16 + fr] =
                (_Float16)(oacc[dj][r] * inv[r]);
}

// ---------------------------------------------------------------- router
__global__ __launch_bounds__(256) void k_router(
    const float* __restrict__ hm, const float* __restrict__ rw,
    float* __restrict__ wdense)
{
    const int tok = blockIdx.x * 4 + (threadIdx.x >> 6);
    const int lane = threadIdx.x & 63;
    __shared__ float lg[4][16];
    const float* hr = hm + (size_t)tok * 2048;
    for (int e = 0; e < 16; e++) {
        float acc = 0.f;
        #pragma unroll
        for (int i = 0; i < 32; i++) acc += hr[i * 64 + lane] * rw[(size_t)e * 2048 + i * 64 + lane];
        #pragma unroll
        for (int m = 1; m < 64; m <<= 1) acc += __shfl_xor(acc, m);
        if (lane == 0) lg[threadIdx.x >> 6][e] = acc;
    }
    __syncthreads();
    if (lane == 0) {
        float* l = lg[threadIdx.x >> 6];
        float mx = l[0];
        for (int e = 1; e < 16; e++) mx = fmaxf(mx, l[e]);
        float p[16]; float sum = 0.f;
        for (int e = 0; e < 16; e++) { p[e] = expf(l[e] - mx); sum += p[e]; }
        for (int e = 0; e < 16; e++) p[e] /= sum;
        bool sel[16]; for (int e = 0; e < 16; e++) sel[e] = false;
        float ssum = 0.f;
        for (int t = 0; t < 8; t++) {
            int bi = -1; float bv = -1.f;
            for (int e = 0; e < 16; e++) if (!sel[e] && p[e] > bv) { bv = p[e]; bi = e; }
            sel[bi] = true; ssum += bv;
        }
        for (int e = 0; e < 16; e++)
            wdense[(size_t)e * 4096 + tok] = sel[e] ? p[e] / ssum : 0.f;
    }
}

// ---------------------------------------------------------------- MoE gate/up
// ab[tok][e*128+mi] = wdense[e][tok] * silu(g) * u.  Same pipeline/swizzle.
__global__ __launch_bounds__(256) void k_moe_gu(
    const _Float16* __restrict__ hm, const _Float16* __restrict__ gw,
    const _Float16* __restrict__ uw, const float* __restrict__ wdense,
    _Float16* __restrict__ ab)
{
    const int r0 = blockIdx.x * 128, e = blockIdx.y;
    const _Float16* G = gw + (size_t)e * 128 * 2048;
    const _Float16* U = uw + (size_t)e * 128 * 2048;
    __shared__ __align__(16) _Float16 As[3][128][32];
    __shared__ __align__(16) _Float16 Gs[3][128][32];
    __shared__ __align__(16) _Float16 Us[3][128][32];
    const int tid = threadIdx.x, lane = tid & 63, wid = tid >> 6;
    const int wr = wid >> 1, wc = wid & 1;
    const int sr = lane >> 2;
    const int scs = ((lane & 3) ^ ((lane >> 3) & 3)) * 8;
    const int fr = lane & 15;
    const int rks = (((lane >> 4) ^ ((fr >> 1) & 3))) * 8;
    const f32x4 z4 = { 0.f, 0.f, 0.f, 0.f };
    f32x4 ag[4][4], au[4][4];
    #pragma unroll
    for (int i = 0; i < 4; i++)
        #pragma unroll
        for (int j = 0; j < 4; j++) { ag[i][j] = z4; au[i][j] = z4; }

    auto stage = [&](int bf, int k0) {
        #pragma unroll
        for (int i = 0; i < 2; i++) {
            int chunk = wid * 2 + i;
            load16_lds(hm + (size_t)(r0 + chunk * 16 + sr) * 2048 + k0 + scs, &As[bf][chunk * 16][0]);
            load16_lds(G + (size_t)(chunk * 16 + sr) * 2048 + k0 + scs, &Gs[bf][chunk * 16][0]);
            load16_lds(U + (size_t)(chunk * 16 + sr) * 2048 + k0 + scs, &Us[bf][chunk * 16][0]);
        }
    };

    stage(0, 0);
    stage(1, 32);
    int cur = 0;
    for (int t = 0; t < 64; t++) {
        if (t < 63) asm volatile("s_waitcnt vmcnt(6)" ::: "memory");
        else        asm volatile("s_waitcnt vmcnt(0)" ::: "memory");
        __builtin_amdgcn_s_barrier();
        f16x8 af[4], bg[4], bu[4];
        #pragma unroll
        for (int i = 0; i < 4; i++)
            af[i] = *reinterpret_cast<const f16x8*>(&As[cur][wr * 64 + i * 16 + fr][rks]);
        #pragma unroll
        for (int j = 0; j < 4; j++) {
            bg[j] = *reinterpret_cast<const f16x8*>(&Gs[cur][wc * 64 + j * 16 + fr][rks]);
            bu[j] = *reinterpret_cast<const f16x8*>(&Us[cur][wc * 64 + j * 16 + fr][rks]);
        }
        if (t + 2 < 64) stage((t + 2) % 3, (t + 2) << 5);
        #pragma unroll
        for (int i = 0; i < 4; i++)
            #pragma unroll
            for (int j = 0; j < 4; j++) {
                ag[i][j] = __builtin_amdgcn_mfma_f32_16x16x32_f16(af[i], bg[j], ag[i][j], 0, 0, 0);
                au[i][j] = __builtin_amdgcn_mfma_f32_16x16x32_f16(af[i], bu[j], au[i][j], 0, 0, 0);
            }
        cur = (cur + 1) % 3;
    }
    #pragma unroll
    for (int i = 0; i < 4; i++) {
        const int rowb = r0 + wr * 64 + i * 16 + (lane >> 4) * 4;
        float wv[4];
        #pragma unroll
        for (int r = 0; r < 4; r++) wv[r] = wdense[(size_t)e * 4096 + rowb + r];
        #pragma unroll
        for (int j = 0; j < 4; j++) {
            const int col = e * 128 + wc * 64 + j * 16 + fr;
            #pragma unroll
            for (int r = 0; r < 4; r++) {
                float g = ag[i][j][r], uu = au[i][j][r];
                float sil = g / (1.f + __expf(-g));
                ab[(size_t)(rowb + r) * 2048 + col] = (_Float16)(sil * uu * wv[r]);
            }
        }
    }
}

// ---------------------------------------------------------------- launch

extern "C" void kernel_launch(void* const* d_in, const int* in_sizes, int n_in,
                              void* d_out, int out_size, void* d_ws, size_t ws_size,
                              hipStream_t stream)
{
    const float* x        = (const float*)d_in[0];
    const float* cosb     = (const float*)d_in[1];
    const float* sinb     = (const float*)d_in[2];
    const float* nattn    = (const float*)d_in[3];
    const float* q_w      = (const float*)d_in[4];
    const float* k_w      = (const float*)d_in[5];
    const float* v_w      = (const float*)d_in[6];
    const float* qn_w     = (const float*)d_in[7];
    const float* kn_w     = (const float*)d_in[8];
    const float* o_w      = (const float*)d_in[9];
    const float* nmlp     = (const float*)d_in[10];
    const float* router_w = (const float*)d_in[11];
    const float* egw      = (const float*)d_in[12];
    const float* euw      = (const float*)d_in[13];
    const float* edw      = (const float*)d_in[14];

    char* w = (char*)d_ws;
    _Float16* qkvw_h = (_Float16*)(w + 0);          // 20.97 MB (q||k||v rows)
    _Float16* ow_h   = (_Float16*)(w + 20971520);   // 16.78 MB
    _Float16* gw_h   = (_Float16*)(w + 37748736);   //  8.39 MB
    _Float16* uw_h   = (_Float16*)(w + 46137344);   //  8.39 MB
    _Float16* dwc_h  = (_Float16*)(w + 54525952);   //  8.39 MB (permuted)
    _Float16* h_h    = (_Float16*)(w + 62914560);   // 16.78 MB (aliased hm_h)
    _Float16* hm_h   = h_h;
    float*    x2     = (float*)(w + 79691776);      // 33.55 MB
    _Float16* qkv_h  = (_Float16*)(w + 113246208);  // 41.94 MB (alias o_h, ab_h)
    _Float16* o_h    = qkv_h;
    _Float16* ab_h   = qkv_h;
    _Float16* q_h    = (_Float16*)(w + 155189248);  // 33.55 MB (alias hm_f)
    float*    hm_f   = (float*)(w + 155189248);
    _Float16* k_h    = (_Float16*)(w + 188743680);  //  4.19 MB
    _Float16* vt_h   = (_Float16*)(w + 192937984);  //  4.19 MB
    float*    wdense = (float*)(w + 197132288);     //  0.26 MB

    k_cast<<<8192, 256, 0, stream>>>(q_w, qkvw_h, 8388608);
    k_cast<<<1024, 256, 0, stream>>>(k_w, qkvw_h + (size_t)4096 * 2048, 1048576);
    k_cast<<<1024, 256, 0, stream>>>(v_w, qkvw_h + (size_t)4608 * 2048, 1048576);
    k_cast<<<8192, 256, 0, stream>>>(o_w, ow_h, 8388608);
    k_cast<<<4096, 256, 0, stream>>>(egw, gw_h, 4194304);
    k_cast<<<4096, 256, 0, stream>>>(euw, uw_h, 4194304);
    k_cast_dw<<<4096, 256, 0, stream>>>(edw, dwc_h);

    k_rmsnorm<<<4096, 256, 0, stream>>>(x, nattn, h_h, nullptr);
    k_gemm<<<dim3(32, 40), 256, 0, stream>>>(h_h, 2048, qkvw_h, 2048,
                                             nullptr, qkv_h, 5120, nullptr, 2048);
    k_qkv_post<<<dim3(4096, 40), 128, 0, stream>>>(qkv_h, cosb, sinb, qn_w, kn_w,
                                                   q_h, k_h, vt_h);
    k_attn<<<dim3(128, 16), 256, 0, stream>>>(q_h, k_h, vt_h, o_h);
    k_gemm<<<dim3(32, 16), 256, 0, stream>>>(o_h, 4096, ow_h, 4096,
                                             x2, nullptr, 2048, x, 4096);
    k_rmsnorm<<<4096, 256, 0, stream>>>(x2, nmlp, hm_h, hm_f);
    k_router<<<1024, 256, 0, stream>>>(hm_f, router_w, wdense);
    k_moe_gu<<<dim3(32, 16), 256, 0, stream>>>(hm_h, gw_h, uw_h, wdense, ab_h);
    k_gemm<<<dim3(32, 16), 256, 0, stream>>>(ab_h, 2048, dwc_h, 2048,
                                             (float*)d_out, nullptr, 2048, x2, 2048);

    (void)in_sizes; (void)n_in; (void)out_size; (void)ws_size;
}

// Round 6
// 565.624 us; speedup vs baseline: 2.0841x; 1.0906x over previous
//
#include <hip/hip_runtime.h>
#include <stdint.h>

typedef _Float16 f16x8 __attribute__((ext_vector_type(8)));
typedef _Float16 f16x4 __attribute__((ext_vector_type(4)));
typedef float    f32x4 __attribute__((ext_vector_type(4)));

__device__ __forceinline__ void load16_lds(const _Float16* g, _Float16* l) {
    __builtin_amdgcn_global_load_lds(
        (const __attribute__((address_space(1))) void*)g,
        (__attribute__((address_space(3))) void*)l, 16, 0, 0);
}

// ---------------------------------------------------------------- casts

__global__ void k_cast(const float* __restrict__ in, _Float16* __restrict__ out, int n) {
    int i = (blockIdx.x * 256 + threadIdx.x) * 4;
    if (i < n) {
        float4 v = *reinterpret_cast<const float4*>(in + i);
        f16x4 o = { (_Float16)v.x, (_Float16)v.y, (_Float16)v.z, (_Float16)v.w };
        *reinterpret_cast<f16x4*>(out + i) = o;
    }
}

// edw[e][dm][mi] (f32) -> dwc[dm][e*128+mi] (f16)
__global__ void k_cast_dw(const float* __restrict__ edw, _Float16* __restrict__ dwc) {
    int t = blockIdx.x * 256 + threadIdx.x;
    int mi4 = (t & 31) * 4;
    int dm = (t >> 5) & 2047;
    int e = t >> 16;
    float4 v = *reinterpret_cast<const float4*>(edw + (((size_t)e * 2048 + dm) << 7) + mi4);
    f16x4 o = { (_Float16)v.x, (_Float16)v.y, (_Float16)v.z, (_Float16)v.w };
    *reinterpret_cast<f16x4*>(dwc + ((size_t)dm << 11) + e * 128 + mi4) = o;
}

// ---------------------------------------------------------------- rmsnorm
__global__ __launch_bounds__(256) void k_rmsnorm(
    const float* __restrict__ x, const float* __restrict__ w,
    _Float16* __restrict__ oh, float* __restrict__ of)
{
    const int row = blockIdx.x, tid = threadIdx.x;
    const float* xr = x + (size_t)row * 2048;
    float4 a = *reinterpret_cast<const float4*>(xr + tid * 8);
    float4 b = *reinterpret_cast<const float4*>(xr + tid * 8 + 4);
    float ss = a.x*a.x + a.y*a.y + a.z*a.z + a.w*a.w
             + b.x*b.x + b.y*b.y + b.z*b.z + b.w*b.w;
    #pragma unroll
    for (int m = 1; m < 64; m <<= 1) ss += __shfl_xor(ss, m);
    __shared__ float red[4];
    if ((tid & 63) == 0) red[tid >> 6] = ss;
    __syncthreads();
    float tot = red[0] + red[1] + red[2] + red[3];
    float r = rsqrtf(tot * (1.f / 2048.f) + 1e-6f);
    float4 wa = *reinterpret_cast<const float4*>(w + tid * 8);
    float4 wb = *reinterpret_cast<const float4*>(w + tid * 8 + 4);
    float o0 = a.x*r*wa.x, o1 = a.y*r*wa.y, o2 = a.z*r*wa.z, o3 = a.w*r*wa.w;
    float o4 = b.x*r*wb.x, o5 = b.y*r*wb.y, o6 = b.z*r*wb.z, o7 = b.w*r*wb.w;
    f16x8 hv = { (_Float16)o0,(_Float16)o1,(_Float16)o2,(_Float16)o3,
                 (_Float16)o4,(_Float16)o5,(_Float16)o6,(_Float16)o7 };
    *reinterpret_cast<f16x8*>(oh + (size_t)row * 2048 + tid * 8) = hv;
    if (of) {
        float4 f0 = { o0, o1, o2, o3 }, f1 = { o4, o5, o6, o7 };
        *reinterpret_cast<float4*>(of + (size_t)row * 2048 + tid * 8) = f0;
        *reinterpret_cast<float4*>(of + (size_t)row * 2048 + tid * 8 + 4) = f1;
    }
}

// ---------------------------------------------------------------- generic GEMM
// C = A @ W^T (+resid). 3-buffer counted-vmcnt pipeline, XOR-swizzled LDS.
__global__ __launch_bounds__(256) void k_gemm(
    const _Float16* __restrict__ A, int lda,
    const _Float16* __restrict__ W, int ldw,
    float* __restrict__ Cf, _Float16* __restrict__ Ch, int ldc,
    const float* __restrict__ resid, int K)
{
    __shared__ __align__(16) _Float16 As[3][128][32];
    __shared__ __align__(16) _Float16 Ws[3][128][32];
    const int r0 = blockIdx.x * 128, c0 = blockIdx.y * 128;
    const int tid = threadIdx.x, lane = tid & 63, wid = tid >> 6;
    const int wr = wid >> 1, wc = wid & 1;
    const int sr = lane >> 2;
    const int scs = ((lane & 3) ^ ((lane >> 3) & 3)) * 8;
    const int fr = lane & 15;
    const int rks = (((lane >> 4) ^ ((fr >> 1) & 3))) * 8;
    const f32x4 z4 = { 0.f, 0.f, 0.f, 0.f };
    f32x4 acc[4][4];
    #pragma unroll
    for (int i = 0; i < 4; i++)
        #pragma unroll
        for (int j = 0; j < 4; j++) acc[i][j] = z4;

    auto stage = [&](int bf, int k0) {
        #pragma unroll
        for (int i = 0; i < 2; i++) {
            int chunk = wid * 2 + i;
            load16_lds(A + (size_t)(r0 + chunk * 16 + sr) * lda + k0 + scs, &As[bf][chunk * 16][0]);
            load16_lds(W + (size_t)(c0 + chunk * 16 + sr) * ldw + k0 + scs, &Ws[bf][chunk * 16][0]);
        }
    };

    const int nt = K >> 5;
    stage(0, 0);
    if (nt > 1) stage(1, 32);
    int cur = 0;
    for (int t = 0; t < nt; t++) {
        if (t < nt - 1) asm volatile("s_waitcnt vmcnt(4)" ::: "memory");
        else            asm volatile("s_waitcnt vmcnt(0)" ::: "memory");
        __builtin_amdgcn_s_barrier();
        f16x8 af[4], bf4[4];
        #pragma unroll
        for (int i = 0; i < 4; i++)
            af[i] = *reinterpret_cast<const f16x8*>(&As[cur][wr * 64 + i * 16 + fr][rks]);
        #pragma unroll
        for (int j = 0; j < 4; j++)
            bf4[j] = *reinterpret_cast<const f16x8*>(&Ws[cur][wc * 64 + j * 16 + fr][rks]);
        if (t + 2 < nt) stage((t + 2) % 3, (t + 2) << 5);
        #pragma unroll
        for (int i = 0; i < 4; i++)
            #pragma unroll
            for (int j = 0; j < 4; j++)
                acc[i][j] = __builtin_amdgcn_mfma_f32_16x16x32_f16(af[i], bf4[j], acc[i][j], 0, 0, 0);
        cur = (cur + 1) % 3;
    }
    #pragma unroll
    for (int i = 0; i < 4; i++) {
        const int rowb = r0 + wr * 64 + i * 16 + (lane >> 4) * 4;
        #pragma unroll
        for (int j = 0; j < 4; j++) {
            const int col = c0 + wc * 64 + j * 16 + fr;
            #pragma unroll
            for (int r = 0; r < 4; r++) {
                size_t idx = (size_t)(rowb + r) * ldc + col;
                float v = acc[i][j][r];
                if (resid) v += resid[idx];
                if (Ch) Ch[idx] = (_Float16)v;
                else    Cf[idx] = v;
            }
        }
    }
}

// ------------------------------------------- per-head RMSNorm + RoPE (wave-per-head)
// grid (4096, 9), block 256 = 4 waves; u = by*4+widx in [0,36): u<32 q-head, else k-head.
// lane l owns the RoPE pair (d=l, d=l+64) -> no LDS, shfl-only RMS.
__global__ __launch_bounds__(256) void k_qkv_post(
    const _Float16* __restrict__ qkv,
    const float* __restrict__ cosb, const float* __restrict__ sinb,
    const float* __restrict__ qn_w, const float* __restrict__ kn_w,
    _Float16* __restrict__ qh, _Float16* __restrict__ kh)
{
    const int tok = blockIdx.x;
    const int u = blockIdx.y * 4 + (threadIdx.x >> 6);
    const int lane = threadIdx.x & 63;
    const int b = tok >> 10, l = tok & 1023;
    const float c0 = cosb[(size_t)tok * 128 + lane];
    const float c1 = cosb[(size_t)tok * 128 + lane + 64];
    const float s0 = sinb[(size_t)tok * 128 + lane];
    const float s1 = sinb[(size_t)tok * 128 + lane + 64];
    if (u < 32) {
        const _Float16* base = qkv + (size_t)tok * 5120 + u * 128;
        float v0 = (float)base[lane], v1 = (float)base[lane + 64];
        float ss = v0 * v0 + v1 * v1;
        #pragma unroll
        for (int m = 1; m < 64; m <<= 1) ss += __shfl_xor(ss, m);
        float rms = rsqrtf(ss * (1.f / 128.f) + 1e-6f);
        float n0 = v0 * rms * qn_w[lane], n1 = v1 * rms * qn_w[lane + 64];
        _Float16* o = qh + (size_t)tok * 4096 + u * 128;
        o[lane]      = (_Float16)(c0 * n0 - s0 * n1);
        o[lane + 64] = (_Float16)(c1 * n1 + s1 * n0);
    } else {
        const int kvh = u - 32;
        const _Float16* base = qkv + (size_t)tok * 5120 + 4096 + kvh * 128;
        float v0 = (float)base[lane], v1 = (float)base[lane + 64];
        float ss = v0 * v0 + v1 * v1;
        #pragma unroll
        for (int m = 1; m < 64; m <<= 1) ss += __shfl_xor(ss, m);
        float rms = rsqrtf(ss * (1.f / 128.f) + 1e-6f);
        float n0 = v0 * rms * kn_w[lane], n1 = v1 * rms * kn_w[lane + 64];
        _Float16* o = kh + (((size_t)(b * 4 + kvh)) * 1024 + l) * 128;
        o[lane]      = (_Float16)(c0 * n0 - s0 * n1);
        o[lane + 64] = (_Float16)(c1 * n1 + s1 * n0);
    }
}

// ---------------------------------------------------------------- V transpose (coalesced)
// qkv[tok][4608+kv*128+d] -> vth[(bkv*128+d)*1024+l]; 64x64 LDS tile.
__global__ __launch_bounds__(256) void k_vt(
    const _Float16* __restrict__ qkv, _Float16* __restrict__ vth)
{
    const int bkv = blockIdx.x;             // b*4+kv
    const int b = bkv >> 2, kv = bkv & 3;
    const int l0 = blockIdx.y * 64, d0 = blockIdx.z * 64;
    __shared__ _Float16 T[64][72];
    const int t = threadIdx.x;
    const int r = t >> 3, c8 = (t & 7) * 8;
    #pragma unroll
    for (int rr = 0; rr < 2; rr++) {
        int l = l0 + r + rr * 32;
        *reinterpret_cast<f16x8*>(&T[r + rr * 32][c8]) =
            *reinterpret_cast<const f16x8*>(
                qkv + (size_t)(b * 1024 + l) * 5120 + 4608 + kv * 128 + d0 + c8);
    }
    __syncthreads();
    #pragma unroll
    for (int rr = 0; rr < 2; rr++) {
        int d = d0 + r + rr * 32;
        f16x8 v;
        #pragma unroll
        for (int j = 0; j < 8; j++) v[j] = T[c8 + j][r + rr * 32];
        *reinterpret_cast<f16x8*>(vth + ((size_t)(bkv * 128 + d)) * 1024 + l0 + c8) = v;
    }
}

// ---------------------------------------------------------------- attention
__global__ __launch_bounds__(256) void k_attn(
    const _Float16* __restrict__ qh, const _Float16* __restrict__ kh,
    const _Float16* __restrict__ vth, _Float16* __restrict__ oh)
{
    const int bh = blockIdx.x;
    const int g = 15 - blockIdx.y;
    const int b = bh >> 5, h = bh & 31, kv = h >> 3;
    const int tid = threadIdx.x, lane = tid & 63, wid = tid >> 6;
    const int fr = lane & 15, fg = lane >> 4;
    const int q0w = g * 64 + wid * 16;

    __shared__ __align__(16) _Float16 Ks[64][128];
    __shared__ __align__(16) _Float16 Vs[128][64];
    __shared__ __align__(16) _Float16 Ps[4][16][72];

    const _Float16* kb = kh + ((size_t)(b * 4 + kv)) * 1024 * 128;
    const _Float16* vb = vth + ((size_t)(b * 4 + kv)) * 128 * 1024;

    f16x8 aq[4];
    {
        const _Float16* qbase = qh + ((size_t)(b * 1024 + q0w + fr)) * 4096 + h * 128;
        #pragma unroll
        for (int kk = 0; kk < 4; kk++)
            aq[kk] = *reinterpret_cast<const f16x8*>(qbase + kk * 32 + fg * 8);
    }

    float m_r[4] = { -1e30f, -1e30f, -1e30f, -1e30f };
    float l_r[4] = { 0.f, 0.f, 0.f, 0.f };
    const f32x4 z4 = { 0.f, 0.f, 0.f, 0.f };
    f32x4 oacc[8];
    #pragma unroll
    for (int dj = 0; dj < 8; dj++) oacc[dj] = z4;

    const int ntiles = g + 1;
    for (int kt = 0; kt < ntiles; kt++) {
        const int key0 = kt * 64;
        #pragma unroll
        for (int i = 0; i < 4; i++) {
            int rr = 16 * wid + 4 * i + (lane >> 4);
            int c16 = (lane & 15) ^ (rr & 7);
            load16_lds(kb + (size_t)(key0 + rr) * 128 + c16 * 8,
                       &Ks[0][0] + (16 * wid + 4 * i) * 128);
        }
        #pragma unroll
        for (int i = 0; i < 4; i++) {
            int rr = 32 * wid + 8 * i + (lane >> 3);
            int c16 = (lane & 7) ^ (rr & 7);
            load16_lds(vb + (size_t)rr * 1024 + key0 + c16 * 8,
                       &Vs[0][0] + (32 * wid + 8 * i) * 64);
        }
        __syncthreads();

        f32x4 sc[4];
        #pragma unroll
        for (int j = 0; j < 4; j++) sc[j] = z4;
        #pragma unroll
        for (int j = 0; j < 4; j++) {
            #pragma unroll
            for (int kk = 0; kk < 4; kk++) {
                f16x8 bk = *reinterpret_cast<const f16x8*>(
                    &Ks[0][0] + (j * 16 + fr) * 128 + (((kk * 4 + fg) ^ (fr & 7)) * 8));
                sc[j] = __builtin_amdgcn_mfma_f32_16x16x32_f16(aq[kk], bk, sc[j], 0, 0, 0);
            }
        }

        const bool lastt = (kt == ntiles - 1);
        float pmax[4] = { -1e30f, -1e30f, -1e30f, -1e30f };
        #pragma unroll
        for (int j = 0; j < 4; j++) {
            const int key = key0 + j * 16 + fr;
            #pragma unroll
            for (int r = 0; r < 4; r++) {
                float v = sc[j][r] * 0.08838834764831845f;
                if (lastt && key > q0w + fg * 4 + r) v = -1e30f;
                sc[j][r] = v;
                pmax[r] = fmaxf(pmax[r], v);
            }
        }
        #pragma unroll
        for (int m = 1; m < 16; m <<= 1)
            #pragma unroll
            for (int r = 0; r < 4; r++) pmax[r] = fmaxf(pmax[r], __shfl_xor(pmax[r], m));
        float alpha[4];
        #pragma unroll
        for (int r = 0; r < 4; r++) {
            float mn = fmaxf(m_r[r], pmax[r]);
            alpha[r] = __expf(m_r[r] - mn);
            m_r[r] = mn;
        }
        float rs[4] = { 0.f, 0.f, 0.f, 0.f };
        #pragma unroll
        for (int j = 0; j < 4; j++)
            #pragma unroll
            for (int r = 0; r < 4; r++) {
                float p = __expf(sc[j][r] - m_r[r]);
                sc[j][r] = p;
                rs[r] += p;
            }
        #pragma unroll
        for (int m = 1; m < 16; m <<= 1)
            #pragma unroll
            for (int r = 0; r < 4; r++) rs[r] += __shfl_xor(rs[r], m);
        #pragma unroll
        for (int r = 0; r < 4; r++) l_r[r] = l_r[r] * alpha[r] + rs[r];
        #pragma unroll
        for (int dj = 0; dj < 8; dj++)
            #pragma unroll
            for (int r = 0; r < 4; r++) oacc[dj][r] *= alpha[r];

        #pragma unroll
        for (int j = 0; j < 4; j++)
            #pragma unroll
            for (int r = 0; r < 4; r++)
                Ps[wid][fg * 4 + r][j * 16 + fr] = (_Float16)sc[j][r];

        #pragma unroll
        for (int ks = 0; ks < 2; ks++) {
            f16x8 ap = *reinterpret_cast<const f16x8*>(&Ps[wid][fr][ks * 32 + fg * 8]);
            #pragma unroll
            for (int dj = 0; dj < 8; dj++) {
                f16x8 bv = *reinterpret_cast<const f16x8*>(
                    &Vs[0][0] + (dj * 16 + fr) * 64 + (((ks * 4 + fg) ^ (fr & 7)) * 8));
                oacc[dj] = __builtin_amdgcn_mfma_f32_16x16x32_f16(ap, bv, oacc[dj], 0, 0, 0);
            }
        }
        __syncthreads();
    }

    float inv[4];
    #pragma unroll
    for (int r = 0; r < 4; r++) inv[r] = 1.f / l_r[r];
    #pragma unroll
    for (int dj = 0; dj < 8; dj++)
        #pragma unroll
        for (int r = 0; r < 4; r++)
            oh[((size_t)(b * 1024 + q0w + fg * 4 + r)) * 4096 + h * 128 + dj * 16 + fr] =
                (_Float16)(oacc[dj][r] * inv[r]);
}

// ---------------------------------------------------------------- router
__global__ __launch_bounds__(256) void k_router(
    const float* __restrict__ hm, const float* __restrict__ rw,
    float* __restrict__ wdense)
{
    const int tok = blockIdx.x * 4 + (threadIdx.x >> 6);
    const int lane = threadIdx.x & 63;
    __shared__ float lg[4][16];
    const float* hr = hm + (size_t)tok * 2048;
    for (int e = 0; e < 16; e++) {
        float acc = 0.f;
        #pragma unroll
        for (int i = 0; i < 32; i++) acc += hr[i * 64 + lane] * rw[(size_t)e * 2048 + i * 64 + lane];
        #pragma unroll
        for (int m = 1; m < 64; m <<= 1) acc += __shfl_xor(acc, m);
        if (lane == 0) lg[threadIdx.x >> 6][e] = acc;
    }
    __syncthreads();
    if (lane == 0) {
        float* l = lg[threadIdx.x >> 6];
        float mx = l[0];
        for (int e = 1; e < 16; e++) mx = fmaxf(mx, l[e]);
        float p[16]; float sum = 0.f;
        for (int e = 0; e < 16; e++) { p[e] = expf(l[e] - mx); sum += p[e]; }
        for (int e = 0; e < 16; e++) p[e] /= sum;
        bool sel[16]; for (int e = 0; e < 16; e++) sel[e] = false;
        float ssum = 0.f;
        for (int t = 0; t < 8; t++) {
            int bi = -1; float bv = -1.f;
            for (int e = 0; e < 16; e++) if (!sel[e] && p[e] > bv) { bv = p[e]; bi = e; }
            sel[bi] = true; ssum += bv;
        }
        for (int e = 0; e < 16; e++)
            wdense[(size_t)e * 4096 + tok] = sel[e] ? p[e] / ssum : 0.f;
    }
}

// ---------------------------------------------------------------- MoE gate/up
// ab[tok][e*128+mi] = wdense[e][tok]*silu(g)*u.  2-buf stage-first + swizzle.
__global__ __launch_bounds__(256) void k_moe_gu(
    const _Float16* __restrict__ hm, const _Float16* __restrict__ gw,
    const _Float16* __restrict__ uw, const float* __restrict__ wdense,
    _Float16* __restrict__ ab)
{
    const int r0 = blockIdx.x * 128, e = blockIdx.y;
    const _Float16* G = gw + (size_t)e * 128 * 2048;
    const _Float16* U = uw + (size_t)e * 128 * 2048;
    __shared__ __align__(16) _Float16 As[2][128][32];
    __shared__ __align__(16) _Float16 Gs[2][128][32];
    __shared__ __align__(16) _Float16 Us[2][128][32];
    const int tid = threadIdx.x, lane = tid & 63, wid = tid >> 6;
    const int wr = wid >> 1, wc = wid & 1;
    const int sr = lane >> 2;
    const int scs = ((lane & 3) ^ ((lane >> 3) & 3)) * 8;
    const int fr = lane & 15;
    const int rks = (((lane >> 4) ^ ((fr >> 1) & 3))) * 8;
    const f32x4 z4 = { 0.f, 0.f, 0.f, 0.f };
    f32x4 ag[4][4], au[4][4];
    #pragma unroll
    for (int i = 0; i < 4; i++)
        #pragma unroll
        for (int j = 0; j < 4; j++) { ag[i][j] = z4; au[i][j] = z4; }

    auto stage = [&](int bf, int k0) {
        #pragma unroll
        for (int i = 0; i < 2; i++) {
            int chunk = wid * 2 + i;
            load16_lds(hm + (size_t)(r0 + chunk * 16 + sr) * 2048 + k0 + scs, &As[bf][chunk * 16][0]);
            load16_lds(G + (size_t)(chunk * 16 + sr) * 2048 + k0 + scs, &Gs[bf][chunk * 16][0]);
            load16_lds(U + (size_t)(chunk * 16 + sr) * 2048 + k0 + scs, &Us[bf][chunk * 16][0]);
        }
    };

    stage(0, 0);
    __syncthreads();
    int cur = 0;
    for (int t = 0; t < 64; t++) {
        if (t + 1 < 64) stage(cur ^ 1, (t + 1) << 5);
        f16x8 af[4], bg[4], bu[4];
        #pragma unroll
        for (int i = 0; i < 4; i++)
            af[i] = *reinterpret_cast<const f16x8*>(&As[cur][wr * 64 + i * 16 + fr][rks]);
        #pragma unroll
        for (int j = 0; j < 4; j++) {
            bg[j] = *reinterpret_cast<const f16x8*>(&Gs[cur][wc * 64 + j * 16 + fr][rks]);
            bu[j] = *reinterpret_cast<const f16x8*>(&Us[cur][wc * 64 + j * 16 + fr][rks]);
        }
        #pragma unroll
        for (int i = 0; i < 4; i++)
            #pragma unroll
            for (int j = 0; j < 4; j++) {
                ag[i][j] = __builtin_amdgcn_mfma_f32_16x16x32_f16(af[i], bg[j], ag[i][j], 0, 0, 0);
                au[i][j] = __builtin_amdgcn_mfma_f32_16x16x32_f16(af[i], bu[j], au[i][j], 0, 0, 0);
            }
        __syncthreads();
        cur ^= 1;
    }
    #pragma unroll
    for (int i = 0; i < 4; i++) {
        const int rowb = r0 + wr * 64 + i * 16 + (lane >> 4) * 4;
        float wv[4];
        #pragma unroll
        for (int r = 0; r < 4; r++) wv[r] = wdense[(size_t)e * 4096 + rowb + r];
        #pragma unroll
        for (int j = 0; j < 4; j++) {
            const int col = e * 128 + wc * 64 + j * 16 + fr;
            #pragma unroll
            for (int r = 0; r < 4; r++) {
                float g = ag[i][j][r], uu = au[i][j][r];
                float sil = g / (1.f + __expf(-g));
                ab[(size_t)(rowb + r) * 2048 + col] = (_Float16)(sil * uu * wv[r]);
            }
        }
    }
}

// ---------------------------------------------------------------- launch

extern "C" void kernel_launch(void* const* d_in, const int* in_sizes, int n_in,
                              void* d_out, int out_size, void* d_ws, size_t ws_size,
                              hipStream_t stream)
{
    const float* x        = (const float*)d_in[0];
    const float* cosb     = (const float*)d_in[1];
    const float* sinb     = (const float*)d_in[2];
    const float* nattn    = (const float*)d_in[3];
    const float* q_w      = (const float*)d_in[4];
    const float* k_w      = (const float*)d_in[5];
    const float* v_w      = (const float*)d_in[6];
    const float* qn_w     = (const float*)d_in[7];
    const float* kn_w     = (const float*)d_in[8];
    const float* o_w      = (const float*)d_in[9];
    const float* nmlp     = (const float*)d_in[10];
    const float* router_w = (const float*)d_in[11];
    const float* egw      = (const float*)d_in[12];
    const float* euw      = (const float*)d_in[13];
    const float* edw      = (const float*)d_in[14];

    char* w = (char*)d_ws;
    _Float16* qkvw_h = (_Float16*)(w + 0);          // 20.97 MB
    _Float16* ow_h   = (_Float16*)(w + 20971520);   // 16.78 MB
    _Float16* gw_h   = (_Float16*)(w + 37748736);   //  8.39 MB
    _Float16* uw_h   = (_Float16*)(w + 46137344);   //  8.39 MB
    _Float16* dwc_h  = (_Float16*)(w + 54525952);   //  8.39 MB
    _Float16* h_h    = (_Float16*)(w + 62914560);   // 16.78 MB
    _Float16* hm_h   = h_h;
    float*    x2     = (float*)(w + 79691776);      // 33.55 MB
    _Float16* qkv_h  = (_Float16*)(w + 113246208);  // 41.94 MB (alias o_h, ab_h)
    _Float16* o_h    = qkv_h;
    _Float16* ab_h   = qkv_h;
    _Float16* q_h    = (_Float16*)(w + 155189248);  // 33.55 MB (alias hm_f)
    float*    hm_f   = (float*)(w + 155189248);
    _Float16* k_h    = (_Float16*)(w + 188743680);  //  4.19 MB
    _Float16* vt_h   = (_Float16*)(w + 192937984);  //  4.19 MB
    float*    wdense = (float*)(w + 197132288);     //  0.26 MB

    k_cast<<<8192, 256, 0, stream>>>(q_w, qkvw_h, 8388608);
    k_cast<<<1024, 256, 0, stream>>>(k_w, qkvw_h + (size_t)4096 * 2048, 1048576);
    k_cast<<<1024, 256, 0, stream>>>(v_w, qkvw_h + (size_t)4608 * 2048, 1048576);
    k_cast<<<8192, 256, 0, stream>>>(o_w, ow_h, 8388608);
    k_cast<<<4096, 256, 0, stream>>>(egw, gw_h, 4194304);
    k_cast<<<4096, 256, 0, stream>>>(euw, uw_h, 4194304);
    k_cast_dw<<<4096, 256, 0, stream>>>(edw, dwc_h);

    k_rmsnorm<<<4096, 256, 0, stream>>>(x, nattn, h_h, nullptr);
    k_gemm<<<dim3(32, 40), 256, 0, stream>>>(h_h, 2048, qkvw_h, 2048,
                                             nullptr, qkv_h, 5120, nullptr, 2048);
    k_qkv_post<<<dim3(4096, 9), 256, 0, stream>>>(qkv_h, cosb, sinb, qn_w, kn_w, q_h, k_h);
    k_vt<<<dim3(16, 16, 2), 256, 0, stream>>>(qkv_h, vt_h);
    k_attn<<<dim3(128, 16), 256, 0, stream>>>(q_h, k_h, vt_h, o_h);
    k_gemm<<<dim3(32, 16), 256, 0, stream>>>(o_h, 4096, ow_h, 4096,
                                             x2, nullptr, 2048, x, 4096);
    k_rmsnorm<<<4096, 256, 0, stream>>>(x2, nmlp, hm_h, hm_f);
    k_router<<<1024, 256, 0, stream>>>(hm_f, router_w, wdense);
    k_moe_gu<<<dim3(32, 16), 256, 0, stream>>>(hm_h, gw_h, uw_h, wdense, ab_h);
    k_gemm<<<dim3(32, 16), 256, 0, stream>>>(ab_h, 2048, dwc_h, 2048,
                                             (float*)d_out, nullptr, 2048, x2, 2048);

    (void)in_sizes; (void)n_in; (void)out_size; (void)ws_size;
}